// Round 7
// baseline (523.691 us; speedup 1.0000x reference)
//
#include <hip/hip_runtime.h>
#include <stdint.h>

#define Hh 12
#define Cc 768
#define Tt 576
#define BTC 1769472L
#define HI_ 24
#define WI_ 24
#define CH 16
#define NCH 36
#define RB 16   // rows per wkv7 block
#define NRB 4   // row-blocks per head

typedef unsigned int uint;
typedef unsigned short ushort;
typedef __attribute__((ext_vector_type(8))) short short8;
typedef __attribute__((ext_vector_type(4))) float f32x4;

__device__ __forceinline__ ushort f2b(float f) {
  uint u = __float_as_uint(f);
  u += 0x7FFFu + ((u >> 16) & 1u);
  return (ushort)(u >> 16);
}
__device__ __forceinline__ float b2f(ushort h) { return __uint_as_float(((uint)h) << 16); }
__device__ __forceinline__ float sigm(float x) { return 1.0f / (1.0f + __expf(-x)); }

// cross-lane helpers: xor1/xor2 via DPP quad_perm (VALU pipe), xor4 via ds_swizzle
__device__ __forceinline__ float dppx1(float x) {
  return __int_as_float(__builtin_amdgcn_mov_dpp(__float_as_int(x), 0xB1, 0xF, 0xF, true));
}
__device__ __forceinline__ float dppx2(float x) {
  return __int_as_float(__builtin_amdgcn_mov_dpp(__float_as_int(x), 0x4E, 0xF, 0xF, true));
}
__device__ __forceinline__ float swz4(float x) {
  return __int_as_float(__builtin_amdgcn_ds_swizzle(__float_as_int(x), 0x101F));
}

// hi/lo convention: every bf16-split buffer holds hi plane at [0, SZ) and lo plane at [SZ, 2*SZ).
#define PUT2(buf, i, SZ, vexpr)                      \
  {                                                  \
    float _v = (vexpr);                              \
    ushort _h = f2b(_v);                             \
    (buf)[i] = _h;                                   \
    (buf)[(long)(SZ) + (i)] = f2b(_v - b2f(_h));     \
  }

// ---------- GEMM 64x64 (fallback for N not multiple of 128) ----------
__global__ __launch_bounds__(256) void gemm_hl(
    const ushort* __restrict__ Ah_, const ushort* __restrict__ Al_,
    const ushort* __restrict__ Bh_, const ushort* __restrict__ Bl_,
    float* __restrict__ C,
    int N, int K, int lda, int ldb, int ldc, long sA, long sB, long sC) {
  Ah_ += (long)blockIdx.z * sA;
  Al_ += (long)blockIdx.z * sA;
  Bh_ += (long)blockIdx.z * sB;
  Bl_ += (long)blockIdx.z * sB;
  C += (long)blockIdx.z * sC;
  __shared__ ushort sAh[64][40], sAl[64][40], sBh[64][40], sBl[64][40];
  const int bm = blockIdx.x * 64, bn = blockIdx.y * 64;
  const int tid = threadIdx.x;
  const int wave = tid >> 6, lane = tid & 63;
  const int wm = (wave >> 1) * 32, wn = (wave & 1) * 32;
  const int srow = tid >> 2, scol = (tid & 3) * 8;
  const int fr = lane & 15, kg = (lane >> 4) * 8;
  f32x4 acc[2][2] = {};
  const int bnrow = bn + srow;
  const bool bok = bnrow < N;
  const ushort* aph = Ah_ + (long)(bm + srow) * lda + scol;
  const ushort* apl = Al_ + (long)(bm + srow) * lda + scol;
  const ushort* bph = Bh_ + (long)bnrow * ldb + scol;
  const ushort* bpl = Bl_ + (long)bnrow * ldb + scol;
  for (int k0 = 0; k0 < K; k0 += 32) {
    short8 avh = *(const short8*)(aph + k0);
    short8 avl = *(const short8*)(apl + k0);
    short8 bvh = {0, 0, 0, 0, 0, 0, 0, 0}, bvl = {0, 0, 0, 0, 0, 0, 0, 0};
    if (bok) { bvh = *(const short8*)(bph + k0); bvl = *(const short8*)(bpl + k0); }
    __syncthreads();
    *(short8*)&sAh[srow][scol] = avh;
    *(short8*)&sAl[srow][scol] = avl;
    *(short8*)&sBh[srow][scol] = bvh;
    *(short8*)&sBl[srow][scol] = bvl;
    __syncthreads();
    short8 bfh[2], bfl[2];
#pragma unroll
    for (int ni = 0; ni < 2; ni++) {
      bfh[ni] = *(const short8*)&sBh[wn + ni * 16 + fr][kg];
      bfl[ni] = *(const short8*)&sBl[wn + ni * 16 + fr][kg];
    }
#pragma unroll
    for (int mi = 0; mi < 2; mi++) {
      short8 afh = *(const short8*)&sAh[wm + mi * 16 + fr][kg];
      short8 afl = *(const short8*)&sAl[wm + mi * 16 + fr][kg];
#pragma unroll
      for (int ni = 0; ni < 2; ni++) {
        acc[mi][ni] = __builtin_amdgcn_mfma_f32_16x16x32_bf16(afh, bfh[ni], acc[mi][ni], 0, 0, 0);
        acc[mi][ni] = __builtin_amdgcn_mfma_f32_16x16x32_bf16(afh, bfl[ni], acc[mi][ni], 0, 0, 0);
        acc[mi][ni] = __builtin_amdgcn_mfma_f32_16x16x32_bf16(afl, bfh[ni], acc[mi][ni], 0, 0, 0);
      }
    }
  }
  const int row4 = (lane >> 4) * 4;
#pragma unroll
  for (int mi = 0; mi < 2; mi++)
#pragma unroll
    for (int ni = 0; ni < 2; ni++) {
      int gc = bn + wn + ni * 16 + fr;
      if (gc < N) {
        long base = (long)(bm + wm + mi * 16 + row4) * ldc + gc;
#pragma unroll
        for (int rr = 0; rr < 4; rr++) C[base + (long)rr * ldc] = acc[mi][ni][rr];
      }
    }
}

// ---------- GEMM 128x128 tile, BK=32; requires M%128==0 and N%128==0 ----------
// 4 waves (2x2), each computes 64x64 = 4x4 frags of 16x16; 48 MFMA per wave per K-step.
__global__ __launch_bounds__(256) void gemm_hl2(
    const ushort* __restrict__ Ah_, const ushort* __restrict__ Al_,
    const ushort* __restrict__ Bh_, const ushort* __restrict__ Bl_,
    float* __restrict__ C,
    int K, int lda, int ldb, int ldc, long sA, long sB, long sC) {
  Ah_ += (long)blockIdx.z * sA;
  Al_ += (long)blockIdx.z * sA;
  Bh_ += (long)blockIdx.z * sB;
  Bl_ += (long)blockIdx.z * sB;
  C += (long)blockIdx.z * sC;
  __shared__ ushort sAh[128][40], sAl[128][40], sBh[128][40], sBl[128][40];  // 40KB
  const int bm = blockIdx.x * 128, bn = blockIdx.y * 128;
  const int tid = threadIdx.x;
  const int wave = tid >> 6, lane = tid & 63;
  const int wm = (wave >> 1) * 64, wn = (wave & 1) * 64;
  const int srow = tid >> 2, scol = (tid & 3) * 8;  // rows srow, srow+64
  const int fr = lane & 15, kg = (lane >> 4) * 8;
  f32x4 acc[4][4] = {};
  const ushort* aph = Ah_ + (long)(bm + srow) * lda + scol;
  const ushort* apl = Al_ + (long)(bm + srow) * lda + scol;
  const ushort* bph = Bh_ + (long)(bn + srow) * ldb + scol;
  const ushort* bpl = Bl_ + (long)(bn + srow) * ldb + scol;
  const long a64 = 64L * lda, b64 = 64L * ldb;
  for (int k0 = 0; k0 < K; k0 += 32) {
    short8 avh0 = *(const short8*)(aph + k0);
    short8 avh1 = *(const short8*)(aph + a64 + k0);
    short8 avl0 = *(const short8*)(apl + k0);
    short8 avl1 = *(const short8*)(apl + a64 + k0);
    short8 bvh0 = *(const short8*)(bph + k0);
    short8 bvh1 = *(const short8*)(bph + b64 + k0);
    short8 bvl0 = *(const short8*)(bpl + k0);
    short8 bvl1 = *(const short8*)(bpl + b64 + k0);
    __syncthreads();
    *(short8*)&sAh[srow][scol] = avh0;
    *(short8*)&sAh[srow + 64][scol] = avh1;
    *(short8*)&sAl[srow][scol] = avl0;
    *(short8*)&sAl[srow + 64][scol] = avl1;
    *(short8*)&sBh[srow][scol] = bvh0;
    *(short8*)&sBh[srow + 64][scol] = bvh1;
    *(short8*)&sBl[srow][scol] = bvl0;
    *(short8*)&sBl[srow + 64][scol] = bvl1;
    __syncthreads();
    short8 bfh[4], bfl[4];
#pragma unroll
    for (int ni = 0; ni < 4; ni++) {
      bfh[ni] = *(const short8*)&sBh[wn + ni * 16 + fr][kg];
      bfl[ni] = *(const short8*)&sBl[wn + ni * 16 + fr][kg];
    }
#pragma unroll
    for (int mi = 0; mi < 4; mi++) {
      short8 afh = *(const short8*)&sAh[wm + mi * 16 + fr][kg];
      short8 afl = *(const short8*)&sAl[wm + mi * 16 + fr][kg];
#pragma unroll
      for (int ni = 0; ni < 4; ni++) {
        acc[mi][ni] = __builtin_amdgcn_mfma_f32_16x16x32_bf16(afh, bfh[ni], acc[mi][ni], 0, 0, 0);
        acc[mi][ni] = __builtin_amdgcn_mfma_f32_16x16x32_bf16(afh, bfl[ni], acc[mi][ni], 0, 0, 0);
        acc[mi][ni] = __builtin_amdgcn_mfma_f32_16x16x32_bf16(afl, bfh[ni], acc[mi][ni], 0, 0, 0);
      }
    }
  }
  const int row4 = (lane >> 4) * 4;
#pragma unroll
  for (int mi = 0; mi < 4; mi++)
#pragma unroll
    for (int ni = 0; ni < 4; ni++) {
      int gc = bn + wn + ni * 16 + fr;
      long base = (long)(bm + wm + mi * 16 + row4) * ldc + gc;
#pragma unroll
      for (int rr = 0; rr < 4; rr++) C[base + (long)rr * ldc] = acc[mi][ni][rr];
    }
}

// ---------- weight prep: transpose + hi/lo split ----------
__global__ __launch_bounds__(256) void conv_bigw(const float* __restrict__ Wr,
                                                 const float* __restrict__ Wk,
                                                 const float* __restrict__ Wv,
                                                 const float* __restrict__ Wo,
                                                 ushort* __restrict__ Wb) {
  long idx = (long)blockIdx.x * 256 + threadIdx.x;  // < 4*589824
  const long WSZ = 589824;
  int seg = (int)(idx / WSZ);
  long off = idx % WSZ;
  const float* s = (seg == 0) ? Wr : (seg == 1) ? Wk : (seg == 2) ? Wv : Wo;
  PUT2(Wb, idx, 2359296L, s[off]);
}

__global__ __launch_bounds__(256) void prep_smallw(
    const float* maa_w1, const float* maa_w2, const float* wd1, const float* wd2,
    const float* a1, const float* a2, const float* kk1, const float* kk2,
    const float* g1, const float* g2, const float* ma1, const float* ma2,
    const float* mk1, const float* mk2, ushort* w1T, ushort* w2T, ushort* wcat1,
    ushort* kk1T, ushort* g1T, ushort* wd2T, ushort* armk2T, ushort* g2T) {
  int idx = blockIdx.x * 256 + threadIdx.x;
  if (idx < 98304) { int n = idx / 768, c = idx % 768; PUT2(w1T, idx, 98304, maa_w1[c * 128 + n]); return; }
  idx -= 98304;
  if (idx < 98304) {
    int f = idx / 24576, r = idx % 24576; int n = r / 32, d = r % 32;
    PUT2(w2T, idx, 98304, maa_w2[(f * 32 + d) * 768 + n]); return;
  }
  idx -= 98304;
  if (idx < 49152) { int n = idx / 768, c = idx % 768; PUT2(wcat1, idx, 86016, wd1[c * 64 + n]); return; }
  idx -= 49152;
  if (idx < 12288) { int n = idx / 768, c = idx % 768; PUT2(wcat1, 49152 + idx, 86016, a1[c * 16 + n]); return; }
  idx -= 12288;
  if (idx < 12288) { int n = idx / 768, c = idx % 768; PUT2(wcat1, 61440 + idx, 86016, ma1[c * 16 + n]); return; }
  idx -= 12288;
  if (idx < 12288) { int n = idx / 768, c = idx % 768; PUT2(wcat1, 73728 + idx, 86016, mk1[c * 16 + n]); return; }
  idx -= 12288;
  if (idx < 12288) { int n = idx / 768, c = idx % 768; PUT2(kk1T, idx, 12288, kk1[c * 16 + n]); return; }
  idx -= 12288;
  if (idx < 98304) { int n = idx / 768, c = idx % 768; PUT2(g1T, idx, 98304, g1[c * 128 + n]); return; }
  idx -= 98304;
  if (idx < 49152) { int n = idx / 64, d = idx % 64; PUT2(wd2T, idx, 49152, wd2[d * 768 + n]); return; }
  idx -= 49152;
  if (idx < 98304) {
    int f = idx / 24576, r = idx % 24576; int n = r / 32, d = r % 32;
    const float* s = (f == 0) ? a2 : (f == 1) ? ma2 : (f == 2) ? mk2 : kk2;
    float v = (d < 16) ? s[d * 768 + n] : 0.0f;
    PUT2(armk2T, idx, 98304, v); return;
  }
  idx -= 98304;
  if (idx < 98304) { int n = idx / 128, d = idx % 128; PUT2(g2T, idx, 98304, g2[d * 768 + n]); }
}

// ---------- elementwise producers (write hi/lo bf16 planes) ----------
__global__ __launch_bounds__(256) void qshift_mix(const float* __restrict__ x,
                                                  const float* __restrict__ maa_x,
                                                  float* __restrict__ xx,
                                                  ushort* __restrict__ xxxs) {
  long idx = (long)blockIdx.x * 256 + threadIdx.x;  // < BTC
  int c = (int)(idx % Cc);
  int bt = (int)(idx / Cc);
  int t = bt % Tt;
  int hh = t / WI_, ww = t % WI_;
  int q = c / 192;
  float s = 0.f;
  if (q == 0) { if (ww > 0) s = x[idx - Cc]; }
  else if (q == 1) { if (ww < WI_ - 1) s = x[idx + Cc]; }
  else if (q == 2) { if (hh > 0) s = x[idx - (long)WI_ * Cc]; }
  else { if (hh < HI_ - 1) s = x[idx + (long)WI_ * Cc]; }
  float xv = x[idx];
  float d = s - xv;
  xx[idx] = d;
  PUT2(xxxs, idx, BTC, xv + d * maa_x[c]);
}

__global__ __launch_bounds__(256) void tanh_split(const float* __restrict__ in,
                                                  ushort* __restrict__ out) {
  int i = blockIdx.x * 256 + threadIdx.x;  // 2304*128
  PUT2(out, i, 294912, tanhf(in[i]));
}

__global__ __launch_bounds__(256) void mix4(const float* __restrict__ x,
                                            const float* __restrict__ xx,
                                            const float* __restrict__ m,
                                            const float* __restrict__ maa_rg,
                                            const float* __restrict__ maa_wa,
                                            const float* __restrict__ maa_k,
                                            const float* __restrict__ maa_v,
                                            ushort* __restrict__ x4s) {
  long idx = (long)blockIdx.x * 256 + threadIdx.x;  // BTC
  int c = (int)(idx % Cc);
  float xv = x[idx], d = xx[idx];
  PUT2(x4s, idx, 4 * BTC, xv + d * (maa_rg[c] + m[idx]));                    // xrg (m0)
  PUT2(x4s, idx + BTC, 4 * BTC, xv + d * (maa_k[c] + m[idx + 2 * BTC]));     // xk  (m2)
  PUT2(x4s, idx + 2 * BTC, 4 * BTC, xv + d * (maa_v[c] + m[idx + 3 * BTC])); // xv  (m3)
  PUT2(x4s, idx + 3 * BTC, 4 * BTC, xv + d * (maa_wa[c] + m[idx + BTC]));    // xwa (m1)
}

__global__ __launch_bounds__(256) void build_a2(const float* __restrict__ wlora,
                                                const float* __restrict__ kklora,
                                                const float* __restrict__ glora,
                                                ushort* __restrict__ A2s,
                                                ushort* __restrict__ glss) {
  int idx = blockIdx.x * 256 + threadIdx.x;
  const int NA2 = 2304 * 160;
  if (idx < NA2) {
    int bt = idx / 160, col = idx % 160;
    float v;
    if (col < 64) v = tanhf(wlora[bt * 112 + col]);
    else if (col < 112) v = wlora[bt * 112 + col];
    else if (col < 128) v = tanhf(kklora[bt * 16 + (col - 112)]);
    else v = 0.0f;
    PUT2(A2s, idx, 368640, v);
    return;
  }
  idx -= NA2;
  PUT2(glss, idx, 294912, sigm(glora[idx]));  // 2304*128
}

// one wave per (bt,h); writes aa/bb/decay/k3 IN PLACE over araw/maraw/mkraw/kkraw.
__global__ __launch_bounds__(256) void post_rwkv(
    const float* __restrict__ k, const float* __restrict__ wraw, const float* __restrict__ w0,
    const float* __restrict__ a0, const float* __restrict__ ma0, const float* __restrict__ mk0,
    float* araw, float* maraw, float* mkraw, float* kkraw) {
  int gw = blockIdx.x * 4 + (threadIdx.x >> 6);  // 0..27647
  int j = threadIdx.x & 63;
  int bt = gw / Hh, h = gw % Hh;
  int c = h * 64 + j;
  long idx = (long)bt * Cc + c;
  float kv = k[idx];
  float kkv = kv + kkraw[idx];
  float ss = kkv * kkv;
  for (int mm = 1; mm < 64; mm <<= 1) ss += __shfl_xor(ss, mm, 64);
  float rn = 1.0f / fmaxf(sqrtf(ss), 1e-12f);
  float kkn = kkv * rn;
  float z = w0[c] + wraw[idx];
  float w = fminf(z, 0.f) - log1pf(__expf(-fabsf(z))) - 0.5f;
  float a = sigm(a0[c] + araw[idx]);
  float ma = sigm(ma0[c] + maraw[idx]);
  float mk = sigm(mk0[c] + mkraw[idx]);
  float k2 = kv * ma + kv * a * (1.f - ma);
  float k3 = k2 * __expf(fminf(w * mk, 0.f));
  araw[idx] = -kkn;          // aa
  maraw[idx] = kkn * a;      // bb
  mkraw[idx] = __expf(w);    // decay d
  kkraw[idx] = k3;           // final k
}

// ---------- WKV7: ROW-SPLIT. 192 blocks (= 48 heads x 4 row-blocks), 128 threads ----------
__global__ __launch_bounds__(128, 1) void wkv7(const float* __restrict__ r,
                                               const float* __restrict__ dd,
                                               const float* __restrict__ kk,
                                               const float* __restrict__ vv,
                                               const float* __restrict__ aa,
                                               const float* __restrict__ bb,
                                               float* __restrict__ y) {
  __shared__ float sc[2][5][CH][64];  // r,d,k,a,b full col-vectors: 40KB
  __shared__ float sv[2][CH][RB];     // v slice for this block's rows: 2KB
  const int blk = blockIdx.x;
  const int bh = blk >> 2;            // head 0..47
  const int rb = blk & 3;             // row-block 0..3
  const int b = bh / Hh, h = bh % Hh;
  const int tid = threadIdx.x;
  const int wave = tid >> 6, lane = tid & 63;
  const int rl = lane >> 3, cg = lane & 7;
  const int row = rb * RB + wave * 8 + rl;   // global state row 0..63
  const int cb = cg * 8;                     // cols [cb, cb+8)
  const int vri = wave * 8 + rl;             // local row in sv
  const long vecbase = ((long)b * Tt) * Cc + h * 64;
  float* py = y + vecbase + row;
  const float* gp[5] = {r, dd, kk, aa, bb};
  float S[8];
#pragma unroll
  for (int u = 0; u < 8; u++) S[u] = 0.f;
  f32x4 gq[10];
  float gv[2];

#define SLOAD(t0)                                                              \
  {                                                                            \
    _Pragma("unroll") for (int q = 0; q < 10; q++) {                           \
      const int arr = q >> 1;                                                  \
      const int i2 = ((q & 1) << 7) + tid;                                     \
      gq[q] = *(const f32x4*)(gp[arr] + vecbase + (long)((t0) + (i2 >> 4)) * Cc \
                              + ((i2 & 15) << 2));                             \
    }                                                                          \
    _Pragma("unroll") for (int j = 0; j < 2; j++) {                            \
      const int i2 = (j << 7) + tid;                                           \
      gv[j] = vv[vecbase + (long)((t0) + (i2 >> 4)) * Cc + rb * RB + (i2 & 15)]; \
    }                                                                          \
  }
#define SWRITE(bi)                                                             \
  {                                                                            \
    _Pragma("unroll") for (int q = 0; q < 10; q++) {                           \
      const int i2 = ((q & 1) << 7) + tid;                                     \
      *(f32x4*)&sc[bi][q >> 1][i2 >> 4][(i2 & 15) << 2] = gq[q];               \
    }                                                                          \
    _Pragma("unroll") for (int j = 0; j < 2; j++) {                            \
      const int i2 = (j << 7) + tid;                                           \
      sv[bi][i2 >> 4][i2 & 15] = gv[j];                                        \
    }                                                                          \
  }
#define WSTEP(pb, t, yoff)                                                     \
  {                                                                            \
    f32x4 A0 = *(const f32x4*)&sc[pb][3][t][cb];                               \
    f32x4 A1 = *(const f32x4*)&sc[pb][3][t][cb + 4];                           \
    f32x4 D0 = *(const f32x4*)&sc[pb][1][t][cb];                               \
    f32x4 D1 = *(const f32x4*)&sc[pb][1][t][cb + 4];                           \
    f32x4 K0 = *(const f32x4*)&sc[pb][2][t][cb];                               \
    f32x4 K1 = *(const f32x4*)&sc[pb][2][t][cb + 4];                           \
    f32x4 B0 = *(const f32x4*)&sc[pb][4][t][cb];                               \
    f32x4 B1 = *(const f32x4*)&sc[pb][4][t][cb + 4];                           \
    f32x4 R0 = *(const f32x4*)&sc[pb][0][t][cb];                               \
    f32x4 R1 = *(const f32x4*)&sc[pb][0][t][cb + 4];                           \
    float V = sv[pb][t][vri];                                                  \
    float p0 = S[0] * A0[0] + S[4] * A1[0];                                    \
    float p1 = S[1] * A0[1] + S[5] * A1[1];                                    \
    float p2 = S[2] * A0[2] + S[6] * A1[2];                                    \
    float p3 = S[3] * A0[3] + S[7] * A1[3];                                    \
    float sa = (p0 + p1) + (p2 + p3);                                          \
    sa += dppx1(sa); sa += dppx2(sa); sa += swz4(sa);                          \
    float q0, q1, q2, q3;                                                      \
    S[0] = fmaf(S[0], D0[0], fmaf(sa, B0[0], V * K0[0])); q0 = S[0] * R0[0];   \
    S[1] = fmaf(S[1], D0[1], fmaf(sa, B0[1], V * K0[1])); q1 = S[1] * R0[1];   \
    S[2] = fmaf(S[2], D0[2], fmaf(sa, B0[2], V * K0[2])); q2 = S[2] * R0[2];   \
    S[3] = fmaf(S[3], D0[3], fmaf(sa, B0[3], V * K0[3])); q3 = S[3] * R0[3];   \
    S[4] = fmaf(S[4], D1[0], fmaf(sa, B1[0], V * K1[0])); q0 += S[4] * R1[0];  \
    S[5] = fmaf(S[5], D1[1], fmaf(sa, B1[1], V * K1[1])); q1 += S[5] * R1[1];  \
    S[6] = fmaf(S[6], D1[2], fmaf(sa, B1[2], V * K1[2])); q2 += S[6] * R1[2];  \
    S[7] = fmaf(S[7], D1[3], fmaf(sa, B1[3], V * K1[3])); q3 += S[7] * R1[3];  \
    float yp = (q0 + q1) + (q2 + q3);                                          \
    yp += dppx1(yp); yp += dppx2(yp); yp += swz4(yp);                          \
    if (cg == 0) py[yoff] = yp;                                                \
  }

  SLOAD(0);
  SWRITE(0);
  __syncthreads();
  SLOAD(CH);
  for (int ch = 0; ch < NCH; ch++) {
    const int pb = ch & 1;
    const long ybase = (long)ch * CH * Cc;
#pragma unroll
    for (int t = 0; t < CH; t++) WSTEP(pb, t, ybase + (long)t * Cc);
    __syncthreads();
    if (ch + 1 < NCH) {
      SWRITE(pb ^ 1);
      if (ch + 2 < NCH) SLOAD((ch + 2) * CH);
    }
    __syncthreads();
  }
#undef SLOAD
#undef SWRITE
#undef WSTEP
}

// ---------- groupnorm + bonus + gate ----------
__global__ __launch_bounds__(256) void gn_bonus_gate(
    const float* __restrict__ y, const float* __restrict__ r, const float* __restrict__ k3,
    const float* __restrict__ v, const float* __restrict__ g, const float* __restrict__ faaaa,
    const float* __restrict__ lns, const float* __restrict__ lnb, ushort* __restrict__ ygs) {
  int gw = blockIdx.x * 4 + (threadIdx.x >> 6);
  int j = threadIdx.x & 63;
  int bt = gw / Hh, h = gw % Hh;
  int c = h * 64 + j;
  long idx = (long)bt * Cc + c;
  float yv = y[idx];
  float s1 = yv, s2 = yv * yv;
  float s3 = r[idx] * k3[idx] * faaaa[c];
  for (int mm = 1; mm < 64; mm <<= 1) {
    s1 += __shfl_xor(s1, mm, 64);
    s2 += __shfl_xor(s2, mm, 64);
    s3 += __shfl_xor(s3, mm, 64);
  }
  float mu = s1 * (1.f / 64.f);
  float var = s2 * (1.f / 64.f) - mu * mu;
  float xn = (yv - mu) * rsqrtf(var + 64e-5f);
  float y2 = xn * lns[c] + lnb[c] + s3 * v[idx];
  PUT2(ygs, idx, BTC, y2 * g[idx]);
}

// ---------- launch ----------
extern "C" void kernel_launch(void* const* d_in, const int* in_sizes, int n_in,
                              void* d_out, int out_size, void* d_ws, size_t ws_size,
                              hipStream_t stream) {
  const float* x = (const float*)d_in[0];
  const float* maa_x = (const float*)d_in[1];
  const float* maa_rg = (const float*)d_in[2];
  const float* maa_wa = (const float*)d_in[3];
  const float* maa_k = (const float*)d_in[4];
  const float* maa_v = (const float*)d_in[5];
  const float* maa_w1 = (const float*)d_in[6];
  const float* maa_w2 = (const float*)d_in[7];
  const float* w0 = (const float*)d_in[8];
  const float* wd1 = (const float*)d_in[9];
  const float* wd2 = (const float*)d_in[10];
  const float* a0 = (const float*)d_in[11];
  const float* a1 = (const float*)d_in[12];
  const float* a2 = (const float*)d_in[13];
  const float* kk1 = (const float*)d_in[14];
  const float* kk2 = (const float*)d_in[15];
  const float* g1 = (const float*)d_in[16];
  const float* g2 = (const float*)d_in[17];
  const float* ma0 = (const float*)d_in[18];
  const float* ma1 = (const float*)d_in[19];
  const float* ma2 = (const float*)d_in[20];
  const float* mk0 = (const float*)d_in[21];
  const float* mk1 = (const float*)d_in[22];
  const float* mk2 = (const float*)d_in[23];
  const float* faaaa = (const float*)d_in[24];
  const float* Wr = (const float*)d_in[25];
  const float* Wk = (const float*)d_in[26];
  const float* Wv = (const float*)d_in[27];
  const float* Wo = (const float*)d_in[28];
  const float* lns = (const float*)d_in[29];
  const float* lnb = (const float*)d_in[30];

  float* fw = (float*)d_ws;
  float* xx = fw;                          // BTC
  float* m = fw + BTC;                     // 4*BTC: m0..m3, later aa/bb/dec/k3
  float* rbuf = fw + 5 * BTC;
  float* kbuf = fw + 6 * BTC;
  float* vbuf = fw + 7 * BTC;
  float* wrawb = fw + 8 * BTC;
  float* gbuf = fw + 9 * BTC;
  float* ybuf = fw + 10 * BTC;
  float* lora_raw = fw + 11 * BTC;         // 294912
  float* wlora = lora_raw + 294912;        // 258048
  float* glora = wlora + 258048;           // 294912
  float* kklora = glora + 294912;          // 36864   (sum = 884736 = BTC/2)
  ushort* ub = (ushort*)(fw + 11 * BTC + 884736);
  ushort* xxxs = ub;   ub += 2 * BTC;
  ushort* x4s = ub;    ub += 8 * BTC;
  ushort* lts = ub;    ub += 2 * 294912;
  ushort* A2s = ub;    ub += 2 * 368640;
  ushort* glss = ub;   ub += 2 * 294912;
  ushort* ygs = ub;    ub += 2 * BTC;
  ushort* Wb = ub;     ub += 2 * 2359296L;
  ushort* w1T = ub;    ub += 2 * 98304;
  ushort* w2T = ub;    ub += 2 * 98304;
  ushort* wcat1 = ub;  ub += 2 * 86016;
  ushort* kk1T = ub;   ub += 2 * 12288;
  ushort* g1T = ub;    ub += 2 * 98304;
  ushort* wd2T = ub;   ub += 2 * 49152;
  ushort* armk2T = ub; ub += 2 * 98304;
  ushort* g2T = ub;    ub += 2 * 98304;

  dim3 blk(256);
  conv_bigw<<<9216, blk, 0, stream>>>(Wr, Wk, Wv, Wo, Wb);
  prep_smallw<<<2496, blk, 0, stream>>>(maa_w1, maa_w2, wd1, wd2, a1, a2, kk1, kk2, g1, g2,
                                        ma1, ma2, mk1, mk2, w1T, w2T, wcat1, kk1T, g1T, wd2T,
                                        armk2T, g2T);
  qshift_mix<<<6912, blk, 0, stream>>>(x, maa_x, xx, xxxs);
  // lora_raw = xxx @ maa_w1  (N=128, K=768)
  gemm_hl2<<<dim3(18, 1, 1), blk, 0, stream>>>(xxxs, xxxs + BTC, w1T, w1T + 98304, lora_raw,
                                               768, 768, 768, 128, 0, 0, 0);
  tanh_split<<<1152, blk, 0, stream>>>(lora_raw, lts);
  // m[f] = lora[:, f*32:+32] @ maa_w2[f]  (z=4, K=32)
  gemm_hl2<<<dim3(18, 6, 4), blk, 0, stream>>>(lts, lts + 294912, w2T, w2T + 98304, m,
                                               32, 128, 32, 768, 32, 24576, BTC);
  mix4<<<6912, blk, 0, stream>>>(x, xx, m, maa_rg, maa_wa, maa_k, maa_v, x4s);
  // r,k,v (z=3, 768x768)
  gemm_hl2<<<dim3(18, 6, 3), blk, 0, stream>>>(x4s, x4s + 4 * BTC, Wb, Wb + 2359296L, rbuf,
                                               768, 768, 768, 768, BTC, 589824, BTC);
  // wlora = xwa @ [wd1|a1|ma1|mk1]  (N=112)
  gemm_hl<<<dim3(36, 2, 1), blk, 0, stream>>>(x4s + 3 * BTC, x4s + 7 * BTC, wcat1, wcat1 + 86016,
                                              wlora, 112, 768, 768, 768, 112, 0, 0, 0);
  // glora = xrg @ g1  (N=128)
  gemm_hl2<<<dim3(18, 1, 1), blk, 0, stream>>>(x4s, x4s + 4 * BTC, g1T, g1T + 98304, glora,
                                               768, 768, 768, 128, 0, 0, 0);
  // kklora = xk @ kk1  (N=16)
  gemm_hl<<<dim3(36, 1, 1), blk, 0, stream>>>(x4s + BTC, x4s + 5 * BTC, kk1T, kk1T + 12288,
                                              kklora, 16, 768, 768, 768, 16, 0, 0, 0);
  build_a2<<<2592, blk, 0, stream>>>(wlora, kklora, glora, A2s, glss);
  // wraw = tanh(wlora[:,0:64]) @ wd2  (K=64)
  gemm_hl2<<<dim3(18, 6, 1), blk, 0, stream>>>(A2s, A2s + 368640, wd2T, wd2T + 49152, wrawb,
                                               64, 160, 64, 768, 0, 0, 0);
  // araw/maraw/mkraw/kkraw  (z=4, K=32 zero-padded)
  gemm_hl2<<<dim3(18, 6, 4), blk, 0, stream>>>(A2s + 64, A2s + 368640 + 64, armk2T,
                                               armk2T + 98304, m, 32, 160, 32, 768,
                                               16, 24576, BTC);
  // g = sigmoid(glora) @ g2  (K=128)
  gemm_hl2<<<dim3(18, 6, 1), blk, 0, stream>>>(glss, glss + 294912, g2T, g2T + 98304, gbuf,
                                               128, 128, 128, 768, 0, 0, 0);
  post_rwkv<<<6912, blk, 0, stream>>>(kbuf, wrawb, w0, a0, ma0, mk0,
                                      m, m + BTC, m + 2 * BTC, m + 3 * BTC);
  wkv7<<<192, dim3(128), 0, stream>>>(rbuf, m + 2 * BTC, m + 3 * BTC, vbuf, m, m + BTC, ybuf);
  gn_bonus_gate<<<6912, blk, 0, stream>>>(ybuf, rbuf, m + 3 * BTC, vbuf, gbuf, faaaa,
                                          lns, lnb, ygs);
  // out = (y*g) @ Wo
  gemm_hl2<<<dim3(18, 6, 1), blk, 0, stream>>>(ygs, ygs + BTC, Wb + 3L * 589824,
                                               Wb + 2359296L + 3L * 589824, (float*)d_out,
                                               768, 768, 768, 768, 0, 0, 0);
}

// Round 8
// 448.999 us; speedup vs baseline: 1.1664x; 1.1664x over previous
//
#include <hip/hip_runtime.h>
#include <stdint.h>

#define Hh 12
#define Cc 768
#define Tt 576
#define BTC 1769472L
#define HI_ 24
#define WI_ 24
#define CH 16
#define NCH 36
#define RB 16   // rows per wkv7 block
#define NRB 4   // row-blocks per head

typedef unsigned int uint;
typedef unsigned short ushort;
typedef __attribute__((ext_vector_type(8))) short short8;
typedef __attribute__((ext_vector_type(4))) float f32x4;

__device__ __forceinline__ ushort f2b(float f) {
  uint u = __float_as_uint(f);
  u += 0x7FFFu + ((u >> 16) & 1u);
  return (ushort)(u >> 16);
}
__device__ __forceinline__ float b2f(ushort h) { return __uint_as_float(((uint)h) << 16); }
__device__ __forceinline__ float sigm(float x) { return 1.0f / (1.0f + __expf(-x)); }

// cross-lane 8-lane reduce, all on VALU pipe:
// xor1/xor2 via DPP quad_perm; xor4 via DPP row_half_mirror (valid AFTER xor1&xor2
// have made 4-groups uniform: lane j^7 holds the same value as lane j^4).
__device__ __forceinline__ float dppx1(float x) {
  return __int_as_float(__builtin_amdgcn_mov_dpp(__float_as_int(x), 0xB1, 0xF, 0xF, true));
}
__device__ __forceinline__ float dppx2(float x) {
  return __int_as_float(__builtin_amdgcn_mov_dpp(__float_as_int(x), 0x4E, 0xF, 0xF, true));
}
__device__ __forceinline__ float mir8(float x) {
  return __int_as_float(__builtin_amdgcn_mov_dpp(__float_as_int(x), 0x141, 0xF, 0xF, true));
}

// hi/lo convention: every bf16-split buffer holds hi plane at [0, SZ) and lo plane at [SZ, 2*SZ).
#define PUT2(buf, i, SZ, vexpr)                      \
  {                                                  \
    float _v = (vexpr);                              \
    ushort _h = f2b(_v);                             \
    (buf)[i] = _h;                                   \
    (buf)[(long)(SZ) + (i)] = f2b(_v - b2f(_h));     \
  }

// ---------- GEMM 64x64 (fallback for N not multiple of 64-tile routing: N=112/16) ----------
__global__ __launch_bounds__(256) void gemm_hl(
    const ushort* __restrict__ Ah_, const ushort* __restrict__ Al_,
    const ushort* __restrict__ Bh_, const ushort* __restrict__ Bl_,
    float* __restrict__ C,
    int N, int K, int lda, int ldb, int ldc, long sA, long sB, long sC) {
  Ah_ += (long)blockIdx.z * sA;
  Al_ += (long)blockIdx.z * sA;
  Bh_ += (long)blockIdx.z * sB;
  Bl_ += (long)blockIdx.z * sB;
  C += (long)blockIdx.z * sC;
  __shared__ ushort sAh[64][40], sAl[64][40], sBh[64][40], sBl[64][40];
  const int bm = blockIdx.x * 64, bn = blockIdx.y * 64;
  const int tid = threadIdx.x;
  const int wave = tid >> 6, lane = tid & 63;
  const int wm = (wave >> 1) * 32, wn = (wave & 1) * 32;
  const int srow = tid >> 2, scol = (tid & 3) * 8;
  const int fr = lane & 15, kg = (lane >> 4) * 8;
  f32x4 acc[2][2] = {};
  const int bnrow = bn + srow;
  const bool bok = bnrow < N;
  const ushort* aph = Ah_ + (long)(bm + srow) * lda + scol;
  const ushort* apl = Al_ + (long)(bm + srow) * lda + scol;
  const ushort* bph = Bh_ + (long)bnrow * ldb + scol;
  const ushort* bpl = Bl_ + (long)bnrow * ldb + scol;
  for (int k0 = 0; k0 < K; k0 += 32) {
    short8 avh = *(const short8*)(aph + k0);
    short8 avl = *(const short8*)(apl + k0);
    short8 bvh = {0, 0, 0, 0, 0, 0, 0, 0}, bvl = {0, 0, 0, 0, 0, 0, 0, 0};
    if (bok) { bvh = *(const short8*)(bph + k0); bvl = *(const short8*)(bpl + k0); }
    __syncthreads();
    *(short8*)&sAh[srow][scol] = avh;
    *(short8*)&sAl[srow][scol] = avl;
    *(short8*)&sBh[srow][scol] = bvh;
    *(short8*)&sBl[srow][scol] = bvl;
    __syncthreads();
    short8 bfh[2], bfl[2];
#pragma unroll
    for (int ni = 0; ni < 2; ni++) {
      bfh[ni] = *(const short8*)&sBh[wn + ni * 16 + fr][kg];
      bfl[ni] = *(const short8*)&sBl[wn + ni * 16 + fr][kg];
    }
#pragma unroll
    for (int mi = 0; mi < 2; mi++) {
      short8 afh = *(const short8*)&sAh[wm + mi * 16 + fr][kg];
      short8 afl = *(const short8*)&sAl[wm + mi * 16 + fr][kg];
#pragma unroll
      for (int ni = 0; ni < 2; ni++) {
        acc[mi][ni] = __builtin_amdgcn_mfma_f32_16x16x32_bf16(afh, bfh[ni], acc[mi][ni], 0, 0, 0);
        acc[mi][ni] = __builtin_amdgcn_mfma_f32_16x16x32_bf16(afh, bfl[ni], acc[mi][ni], 0, 0, 0);
        acc[mi][ni] = __builtin_amdgcn_mfma_f32_16x16x32_bf16(afl, bfh[ni], acc[mi][ni], 0, 0, 0);
      }
    }
  }
  const int row4 = (lane >> 4) * 4;
#pragma unroll
  for (int mi = 0; mi < 2; mi++)
#pragma unroll
    for (int ni = 0; ni < 2; ni++) {
      int gc = bn + wn + ni * 16 + fr;
      if (gc < N) {
        long base = (long)(bm + wm + mi * 16 + row4) * ldc + gc;
#pragma unroll
        for (int rr = 0; rr < 4; rr++) C[base + (long)rr * ldc] = acc[mi][ni][rr];
      }
    }
}

// ---------- GEMM 128x64 tile, BK=32; requires M%128==0, N%64==0 ----------
// 4 waves (2 row-groups x 2 col-groups), each 64x32 = 4x2 frags; 24 MFMA : 12 ds_read_b128
// per wave per K-step. LDS 30KB -> ~4 blocks/CU co-resident.
__global__ __launch_bounds__(256) void gemm_hl3(
    const ushort* __restrict__ Ah_, const ushort* __restrict__ Al_,
    const ushort* __restrict__ Bh_, const ushort* __restrict__ Bl_,
    float* __restrict__ C,
    int K, int lda, int ldb, int ldc, long sA, long sB, long sC) {
  Ah_ += (long)blockIdx.z * sA;
  Al_ += (long)blockIdx.z * sA;
  Bh_ += (long)blockIdx.z * sB;
  Bl_ += (long)blockIdx.z * sB;
  C += (long)blockIdx.z * sC;
  __shared__ ushort sAh[128][40], sAl[128][40], sBh[64][40], sBl[64][40];  // 30KB
  const int bm = blockIdx.x * 128, bn = blockIdx.y * 64;
  const int tid = threadIdx.x;
  const int wave = tid >> 6, lane = tid & 63;
  const int wm = (wave >> 1) * 64, wn = (wave & 1) * 32;
  const int srow = tid >> 2, scol = (tid & 3) * 8;
  const int fr = lane & 15, kg = (lane >> 4) * 8;
  f32x4 acc[4][2] = {};
  const ushort* aph = Ah_ + (long)(bm + srow) * lda + scol;
  const ushort* apl = Al_ + (long)(bm + srow) * lda + scol;
  const ushort* bph = Bh_ + (long)(bn + srow) * ldb + scol;
  const ushort* bpl = Bl_ + (long)(bn + srow) * ldb + scol;
  const long a64 = 64L * lda;
  for (int k0 = 0; k0 < K; k0 += 32) {
    short8 avh0 = *(const short8*)(aph + k0);
    short8 avh1 = *(const short8*)(aph + a64 + k0);
    short8 avl0 = *(const short8*)(apl + k0);
    short8 avl1 = *(const short8*)(apl + a64 + k0);
    short8 bvh0 = *(const short8*)(bph + k0);
    short8 bvl0 = *(const short8*)(bpl + k0);
    __syncthreads();
    *(short8*)&sAh[srow][scol] = avh0;
    *(short8*)&sAh[srow + 64][scol] = avh1;
    *(short8*)&sAl[srow][scol] = avl0;
    *(short8*)&sAl[srow + 64][scol] = avl1;
    *(short8*)&sBh[srow][scol] = bvh0;
    *(short8*)&sBl[srow][scol] = bvl0;
    __syncthreads();
    short8 bfh[2], bfl[2];
#pragma unroll
    for (int ni = 0; ni < 2; ni++) {
      bfh[ni] = *(const short8*)&sBh[wn + ni * 16 + fr][kg];
      bfl[ni] = *(const short8*)&sBl[wn + ni * 16 + fr][kg];
    }
#pragma unroll
    for (int mi = 0; mi < 4; mi++) {
      short8 afh = *(const short8*)&sAh[wm + mi * 16 + fr][kg];
      short8 afl = *(const short8*)&sAl[wm + mi * 16 + fr][kg];
#pragma unroll
      for (int ni = 0; ni < 2; ni++) {
        acc[mi][ni] = __builtin_amdgcn_mfma_f32_16x16x32_bf16(afh, bfh[ni], acc[mi][ni], 0, 0, 0);
        acc[mi][ni] = __builtin_amdgcn_mfma_f32_16x16x32_bf16(afh, bfl[ni], acc[mi][ni], 0, 0, 0);
        acc[mi][ni] = __builtin_amdgcn_mfma_f32_16x16x32_bf16(afl, bfh[ni], acc[mi][ni], 0, 0, 0);
      }
    }
  }
  const int row4 = (lane >> 4) * 4;
#pragma unroll
  for (int mi = 0; mi < 4; mi++)
#pragma unroll
    for (int ni = 0; ni < 2; ni++) {
      int gc = bn + wn + ni * 16 + fr;
      long base = (long)(bm + wm + mi * 16 + row4) * ldc + gc;
#pragma unroll
      for (int rr = 0; rr < 4; rr++) C[base + (long)rr * ldc] = acc[mi][ni][rr];
    }
}

// ---------- weight prep: transpose + hi/lo split ----------
__global__ __launch_bounds__(256) void conv_bigw(const float* __restrict__ Wr,
                                                 const float* __restrict__ Wk,
                                                 const float* __restrict__ Wv,
                                                 const float* __restrict__ Wo,
                                                 ushort* __restrict__ Wb) {
  long idx = (long)blockIdx.x * 256 + threadIdx.x;  // < 4*589824
  const long WSZ = 589824;
  int seg = (int)(idx / WSZ);
  long off = idx % WSZ;
  const float* s = (seg == 0) ? Wr : (seg == 1) ? Wk : (seg == 2) ? Wv : Wo;
  PUT2(Wb, idx, 2359296L, s[off]);
}

__global__ __launch_bounds__(256) void prep_smallw(
    const float* maa_w1, const float* maa_w2, const float* wd1, const float* wd2,
    const float* a1, const float* a2, const float* kk1, const float* kk2,
    const float* g1, const float* g2, const float* ma1, const float* ma2,
    const float* mk1, const float* mk2, ushort* w1T, ushort* w2T, ushort* wcat1,
    ushort* kk1T, ushort* g1T, ushort* wd2T, ushort* armk2T, ushort* g2T) {
  int idx = blockIdx.x * 256 + threadIdx.x;
  if (idx < 98304) { int n = idx / 768, c = idx % 768; PUT2(w1T, idx, 98304, maa_w1[c * 128 + n]); return; }
  idx -= 98304;
  if (idx < 98304) {
    int f = idx / 24576, r = idx % 24576; int n = r / 32, d = r % 32;
    PUT2(w2T, idx, 98304, maa_w2[(f * 32 + d) * 768 + n]); return;
  }
  idx -= 98304;
  if (idx < 49152) { int n = idx / 768, c = idx % 768; PUT2(wcat1, idx, 86016, wd1[c * 64 + n]); return; }
  idx -= 49152;
  if (idx < 12288) { int n = idx / 768, c = idx % 768; PUT2(wcat1, 49152 + idx, 86016, a1[c * 16 + n]); return; }
  idx -= 12288;
  if (idx < 12288) { int n = idx / 768, c = idx % 768; PUT2(wcat1, 61440 + idx, 86016, ma1[c * 16 + n]); return; }
  idx -= 12288;
  if (idx < 12288) { int n = idx / 768, c = idx % 768; PUT2(wcat1, 73728 + idx, 86016, mk1[c * 16 + n]); return; }
  idx -= 12288;
  if (idx < 12288) { int n = idx / 768, c = idx % 768; PUT2(kk1T, idx, 12288, kk1[c * 16 + n]); return; }
  idx -= 12288;
  if (idx < 98304) { int n = idx / 768, c = idx % 768; PUT2(g1T, idx, 98304, g1[c * 128 + n]); return; }
  idx -= 98304;
  if (idx < 49152) { int n = idx / 64, d = idx % 64; PUT2(wd2T, idx, 49152, wd2[d * 768 + n]); return; }
  idx -= 49152;
  if (idx < 98304) {
    int f = idx / 24576, r = idx % 24576; int n = r / 32, d = r % 32;
    const float* s = (f == 0) ? a2 : (f == 1) ? ma2 : (f == 2) ? mk2 : kk2;
    float v = (d < 16) ? s[d * 768 + n] : 0.0f;
    PUT2(armk2T, idx, 98304, v); return;
  }
  idx -= 98304;
  if (idx < 98304) { int n = idx / 128, d = idx % 128; PUT2(g2T, idx, 98304, g2[d * 768 + n]); }
}

// ---------- elementwise producers (write hi/lo bf16 planes) ----------
__global__ __launch_bounds__(256) void qshift_mix(const float* __restrict__ x,
                                                  const float* __restrict__ maa_x,
                                                  float* __restrict__ xx,
                                                  ushort* __restrict__ xxxs) {
  long idx = (long)blockIdx.x * 256 + threadIdx.x;  // < BTC
  int c = (int)(idx % Cc);
  int bt = (int)(idx / Cc);
  int t = bt % Tt;
  int hh = t / WI_, ww = t % WI_;
  int q = c / 192;
  float s = 0.f;
  if (q == 0) { if (ww > 0) s = x[idx - Cc]; }
  else if (q == 1) { if (ww < WI_ - 1) s = x[idx + Cc]; }
  else if (q == 2) { if (hh > 0) s = x[idx - (long)WI_ * Cc]; }
  else { if (hh < HI_ - 1) s = x[idx + (long)WI_ * Cc]; }
  float xv = x[idx];
  float d = s - xv;
  xx[idx] = d;
  PUT2(xxxs, idx, BTC, xv + d * maa_x[c]);
}

__global__ __launch_bounds__(256) void tanh_split(const float* __restrict__ in,
                                                  ushort* __restrict__ out) {
  int i = blockIdx.x * 256 + threadIdx.x;  // 2304*128
  PUT2(out, i, 294912, tanhf(in[i]));
}

__global__ __launch_bounds__(256) void mix4(const float* __restrict__ x,
                                            const float* __restrict__ xx,
                                            const float* __restrict__ m,
                                            const float* __restrict__ maa_rg,
                                            const float* __restrict__ maa_wa,
                                            const float* __restrict__ maa_k,
                                            const float* __restrict__ maa_v,
                                            ushort* __restrict__ x4s) {
  long idx = (long)blockIdx.x * 256 + threadIdx.x;  // BTC
  int c = (int)(idx % Cc);
  float xv = x[idx], d = xx[idx];
  PUT2(x4s, idx, 4 * BTC, xv + d * (maa_rg[c] + m[idx]));                    // xrg (m0)
  PUT2(x4s, idx + BTC, 4 * BTC, xv + d * (maa_k[c] + m[idx + 2 * BTC]));     // xk  (m2)
  PUT2(x4s, idx + 2 * BTC, 4 * BTC, xv + d * (maa_v[c] + m[idx + 3 * BTC])); // xv  (m3)
  PUT2(x4s, idx + 3 * BTC, 4 * BTC, xv + d * (maa_wa[c] + m[idx + BTC]));    // xwa (m1)
}

__global__ __launch_bounds__(256) void build_a2(const float* __restrict__ wlora,
                                                const float* __restrict__ kklora,
                                                const float* __restrict__ glora,
                                                ushort* __restrict__ A2s,
                                                ushort* __restrict__ glss) {
  int idx = blockIdx.x * 256 + threadIdx.x;
  const int NA2 = 2304 * 160;
  if (idx < NA2) {
    int bt = idx / 160, col = idx % 160;
    float v;
    if (col < 64) v = tanhf(wlora[bt * 112 + col]);
    else if (col < 112) v = wlora[bt * 112 + col];
    else if (col < 128) v = tanhf(kklora[bt * 16 + (col - 112)]);
    else v = 0.0f;
    PUT2(A2s, idx, 368640, v);
    return;
  }
  idx -= NA2;
  PUT2(glss, idx, 294912, sigm(glora[idx]));  // 2304*128
}

// one wave per (bt,h); writes aa/bb/decay/k3 IN PLACE over araw/maraw/mkraw/kkraw.
__global__ __launch_bounds__(256) void post_rwkv(
    const float* __restrict__ k, const float* __restrict__ wraw, const float* __restrict__ w0,
    const float* __restrict__ a0, const float* __restrict__ ma0, const float* __restrict__ mk0,
    float* araw, float* maraw, float* mkraw, float* kkraw) {
  int gw = blockIdx.x * 4 + (threadIdx.x >> 6);  // 0..27647
  int j = threadIdx.x & 63;
  int bt = gw / Hh, h = gw % Hh;
  int c = h * 64 + j;
  long idx = (long)bt * Cc + c;
  float kv = k[idx];
  float kkv = kv + kkraw[idx];
  float ss = kkv * kkv;
  for (int mm = 1; mm < 64; mm <<= 1) ss += __shfl_xor(ss, mm, 64);
  float rn = 1.0f / fmaxf(sqrtf(ss), 1e-12f);
  float kkn = kkv * rn;
  float z = w0[c] + wraw[idx];
  float w = fminf(z, 0.f) - log1pf(__expf(-fabsf(z))) - 0.5f;
  float a = sigm(a0[c] + araw[idx]);
  float ma = sigm(ma0[c] + maraw[idx]);
  float mk = sigm(mk0[c] + mkraw[idx]);
  float k2 = kv * ma + kv * a * (1.f - ma);
  float k3 = k2 * __expf(fminf(w * mk, 0.f));
  araw[idx] = -kkn;          // aa
  maraw[idx] = kkn * a;      // bb
  mkraw[idx] = __expf(w);    // decay d
  kkraw[idx] = k3;           // final k
}

// ---------- WKV7: ROW-SPLIT, 192 blocks, 128 threads; DPP-only reduce + X/Y prefetch ----------
__global__ __launch_bounds__(128, 1) void wkv7(const float* __restrict__ r,
                                               const float* __restrict__ dd,
                                               const float* __restrict__ kk,
                                               const float* __restrict__ vv,
                                               const float* __restrict__ aa,
                                               const float* __restrict__ bb,
                                               float* __restrict__ y) {
  __shared__ float sc[2][5][CH][64];  // r,d,k,a,b full col-vectors: 40KB
  __shared__ float sv[2][CH][RB];     // v slice for this block's rows: 2KB
  const int blk = blockIdx.x;
  const int bh = blk >> 2;            // head 0..47
  const int rb = blk & 3;             // row-block 0..3
  const int b = bh / Hh, h = bh % Hh;
  const int tid = threadIdx.x;
  const int wave = tid >> 6, lane = tid & 63;
  const int rl = lane >> 3, cg = lane & 7;
  const int row = rb * RB + wave * 8 + rl;   // global state row 0..63
  const int cb = cg * 8;                     // cols [cb, cb+8)
  const int vri = wave * 8 + rl;             // local row in sv
  const long vecbase = ((long)b * Tt) * Cc + h * 64;
  float* py = y + vecbase + row;
  const float* gp[5] = {r, dd, kk, aa, bb};
  float S[8];
#pragma unroll
  for (int u = 0; u < 8; u++) S[u] = 0.f;
  f32x4 gq[10];
  float gv[2];
  f32x4 Xq[10], Yq[10];
  float Xv, Yv;

#define SLOAD(t0)                                                              \
  {                                                                            \
    _Pragma("unroll") for (int q = 0; q < 10; q++) {                           \
      const int arr = q >> 1;                                                  \
      const int i2 = ((q & 1) << 7) + tid;                                     \
      gq[q] = *(const f32x4*)(gp[arr] + vecbase + (long)((t0) + (i2 >> 4)) * Cc \
                              + ((i2 & 15) << 2));                             \
    }                                                                          \
    _Pragma("unroll") for (int j = 0; j < 2; j++) {                            \
      const int i2 = (j << 7) + tid;                                           \
      gv[j] = vv[vecbase + (long)((t0) + (i2 >> 4)) * Cc + rb * RB + (i2 & 15)]; \
    }                                                                          \
  }
#define SWRITE(bi)                                                             \
  {                                                                            \
    _Pragma("unroll") for (int q = 0; q < 10; q++) {                           \
      const int i2 = ((q & 1) << 7) + tid;                                     \
      *(f32x4*)&sc[bi][q >> 1][i2 >> 4][(i2 & 15) << 2] = gq[q];               \
    }                                                                          \
    _Pragma("unroll") for (int j = 0; j < 2; j++) {                            \
      const int i2 = (j << 7) + tid;                                           \
      sv[bi][i2 >> 4][i2 & 15] = gv[j];                                        \
    }                                                                          \
  }
// LREAD: LDS -> regs. Order: A(sa chain first), D,K,B,R. V from sv.
#define LREAD(Q, Vv_, pb, t)                                                   \
  {                                                                            \
    Q[0] = *(const f32x4*)&sc[pb][3][t][cb];                                   \
    Q[1] = *(const f32x4*)&sc[pb][3][t][cb + 4];                               \
    Q[2] = *(const f32x4*)&sc[pb][1][t][cb];                                   \
    Q[3] = *(const f32x4*)&sc[pb][1][t][cb + 4];                               \
    Q[4] = *(const f32x4*)&sc[pb][2][t][cb];                                   \
    Q[5] = *(const f32x4*)&sc[pb][2][t][cb + 4];                               \
    Q[6] = *(const f32x4*)&sc[pb][4][t][cb];                                   \
    Q[7] = *(const f32x4*)&sc[pb][4][t][cb + 4];                               \
    Q[8] = *(const f32x4*)&sc[pb][0][t][cb];                                   \
    Q[9] = *(const f32x4*)&sc[pb][0][t][cb + 4];                               \
    Vv_ = sv[pb][t][vri];                                                      \
  }
#define WCOMP(Q, Vv_, yoff)                                                    \
  {                                                                            \
    float p0 = S[0] * Q[0][0] + S[4] * Q[1][0];                                \
    float p1 = S[1] * Q[0][1] + S[5] * Q[1][1];                                \
    float p2 = S[2] * Q[0][2] + S[6] * Q[1][2];                                \
    float p3 = S[3] * Q[0][3] + S[7] * Q[1][3];                                \
    float sa = (p0 + p1) + (p2 + p3);                                          \
    sa += dppx1(sa); sa += dppx2(sa); sa += mir8(sa);                          \
    float q0, q1, q2, q3;                                                      \
    S[0] = fmaf(S[0], Q[2][0], fmaf(sa, Q[6][0], Vv_ * Q[4][0])); q0 = S[0] * Q[8][0]; \
    S[1] = fmaf(S[1], Q[2][1], fmaf(sa, Q[6][1], Vv_ * Q[4][1])); q1 = S[1] * Q[8][1]; \
    S[2] = fmaf(S[2], Q[2][2], fmaf(sa, Q[6][2], Vv_ * Q[4][2])); q2 = S[2] * Q[8][2]; \
    S[3] = fmaf(S[3], Q[2][3], fmaf(sa, Q[6][3], Vv_ * Q[4][3])); q3 = S[3] * Q[8][3]; \
    S[4] = fmaf(S[4], Q[3][0], fmaf(sa, Q[7][0], Vv_ * Q[5][0])); q0 += S[4] * Q[9][0]; \
    S[5] = fmaf(S[5], Q[3][1], fmaf(sa, Q[7][1], Vv_ * Q[5][1])); q1 += S[5] * Q[9][1]; \
    S[6] = fmaf(S[6], Q[3][2], fmaf(sa, Q[7][2], Vv_ * Q[5][2])); q2 += S[6] * Q[9][2]; \
    S[7] = fmaf(S[7], Q[3][3], fmaf(sa, Q[7][3], Vv_ * Q[5][3])); q3 += S[7] * Q[9][3]; \
    float yp = (q0 + q1) + (q2 + q3);                                          \
    yp += dppx1(yp); yp += dppx2(yp); yp += mir8(yp);                          \
    if (cg == 0) py[yoff] = yp;                                                \
  }

  SLOAD(0);
  SWRITE(0);
  __syncthreads();
  SLOAD(CH);
  for (int ch = 0; ch < NCH; ch++) {
    const int pb = ch & 1;
    const long ybase = (long)ch * CH * Cc;
    LREAD(Xq, Xv, pb, 0);
#pragma unroll
    for (int t = 0; t < CH; t += 2) {
      LREAD(Yq, Yv, pb, t + 1);
      WCOMP(Xq, Xv, ybase + (long)t * Cc);
      if (t + 2 < CH) LREAD(Xq, Xv, pb, t + 2);
      WCOMP(Yq, Yv, ybase + (long)(t + 1) * Cc);
    }
    __syncthreads();
    if (ch + 1 < NCH) {
      SWRITE(pb ^ 1);
      if (ch + 2 < NCH) SLOAD((ch + 2) * CH);
    }
    __syncthreads();
  }
#undef SLOAD
#undef SWRITE
#undef LREAD
#undef WCOMP
}

// ---------- groupnorm + bonus + gate ----------
__global__ __launch_bounds__(256) void gn_bonus_gate(
    const float* __restrict__ y, const float* __restrict__ r, const float* __restrict__ k3,
    const float* __restrict__ v, const float* __restrict__ g, const float* __restrict__ faaaa,
    const float* __restrict__ lns, const float* __restrict__ lnb, ushort* __restrict__ ygs) {
  int gw = blockIdx.x * 4 + (threadIdx.x >> 6);
  int j = threadIdx.x & 63;
  int bt = gw / Hh, h = gw % Hh;
  int c = h * 64 + j;
  long idx = (long)bt * Cc + c;
  float yv = y[idx];
  float s1 = yv, s2 = yv * yv;
  float s3 = r[idx] * k3[idx] * faaaa[c];
  for (int mm = 1; mm < 64; mm <<= 1) {
    s1 += __shfl_xor(s1, mm, 64);
    s2 += __shfl_xor(s2, mm, 64);
    s3 += __shfl_xor(s3, mm, 64);
  }
  float mu = s1 * (1.f / 64.f);
  float var = s2 * (1.f / 64.f) - mu * mu;
  float xn = (yv - mu) * rsqrtf(var + 64e-5f);
  float y2 = xn * lns[c] + lnb[c] + s3 * v[idx];
  PUT2(ygs, idx, BTC, y2 * g[idx]);
}

// ---------- launch ----------
extern "C" void kernel_launch(void* const* d_in, const int* in_sizes, int n_in,
                              void* d_out, int out_size, void* d_ws, size_t ws_size,
                              hipStream_t stream) {
  const float* x = (const float*)d_in[0];
  const float* maa_x = (const float*)d_in[1];
  const float* maa_rg = (const float*)d_in[2];
  const float* maa_wa = (const float*)d_in[3];
  const float* maa_k = (const float*)d_in[4];
  const float* maa_v = (const float*)d_in[5];
  const float* maa_w1 = (const float*)d_in[6];
  const float* maa_w2 = (const float*)d_in[7];
  const float* w0 = (const float*)d_in[8];
  const float* wd1 = (const float*)d_in[9];
  const float* wd2 = (const float*)d_in[10];
  const float* a0 = (const float*)d_in[11];
  const float* a1 = (const float*)d_in[12];
  const float* a2 = (const float*)d_in[13];
  const float* kk1 = (const float*)d_in[14];
  const float* kk2 = (const float*)d_in[15];
  const float* g1 = (const float*)d_in[16];
  const float* g2 = (const float*)d_in[17];
  const float* ma0 = (const float*)d_in[18];
  const float* ma1 = (const float*)d_in[19];
  const float* ma2 = (const float*)d_in[20];
  const float* mk0 = (const float*)d_in[21];
  const float* mk1 = (const float*)d_in[22];
  const float* mk2 = (const float*)d_in[23];
  const float* faaaa = (const float*)d_in[24];
  const float* Wr = (const float*)d_in[25];
  const float* Wk = (const float*)d_in[26];
  const float* Wv = (const float*)d_in[27];
  const float* Wo = (const float*)d_in[28];
  const float* lns = (const float*)d_in[29];
  const float* lnb = (const float*)d_in[30];

  float* fw = (float*)d_ws;
  float* xx = fw;                          // BTC
  float* m = fw + BTC;                     // 4*BTC: m0..m3, later aa/bb/dec/k3
  float* rbuf = fw + 5 * BTC;
  float* kbuf = fw + 6 * BTC;
  float* vbuf = fw + 7 * BTC;
  float* wrawb = fw + 8 * BTC;
  float* gbuf = fw + 9 * BTC;
  float* ybuf = fw + 10 * BTC;
  float* lora_raw = fw + 11 * BTC;         // 294912
  float* wlora = lora_raw + 294912;        // 258048
  float* glora = wlora + 258048;           // 294912
  float* kklora = glora + 294912;          // 36864   (sum = 884736 = BTC/2)
  ushort* ub = (ushort*)(fw + 11 * BTC + 884736);
  ushort* xxxs = ub;   ub += 2 * BTC;
  ushort* x4s = ub;    ub += 8 * BTC;
  ushort* lts = ub;    ub += 2 * 294912;
  ushort* A2s = ub;    ub += 2 * 368640;
  ushort* glss = ub;   ub += 2 * 294912;
  ushort* ygs = ub;    ub += 2 * BTC;
  ushort* Wb = ub;     ub += 2 * 2359296L;
  ushort* w1T = ub;    ub += 2 * 98304;
  ushort* w2T = ub;    ub += 2 * 98304;
  ushort* wcat1 = ub;  ub += 2 * 86016;
  ushort* kk1T = ub;   ub += 2 * 12288;
  ushort* g1T = ub;    ub += 2 * 98304;
  ushort* wd2T = ub;   ub += 2 * 49152;
  ushort* armk2T = ub; ub += 2 * 98304;
  ushort* g2T = ub;    ub += 2 * 98304;

  dim3 blk(256);
  conv_bigw<<<9216, blk, 0, stream>>>(Wr, Wk, Wv, Wo, Wb);
  prep_smallw<<<2496, blk, 0, stream>>>(maa_w1, maa_w2, wd1, wd2, a1, a2, kk1, kk2, g1, g2,
                                        ma1, ma2, mk1, mk2, w1T, w2T, wcat1, kk1T, g1T, wd2T,
                                        armk2T, g2T);
  qshift_mix<<<6912, blk, 0, stream>>>(x, maa_x, xx, xxxs);
  // lora_raw = xxx @ maa_w1  (N=128, K=768)
  gemm_hl3<<<dim3(18, 2, 1), blk, 0, stream>>>(xxxs, xxxs + BTC, w1T, w1T + 98304, lora_raw,
                                               768, 768, 768, 128, 0, 0, 0);
  tanh_split<<<1152, blk, 0, stream>>>(lora_raw, lts);
  // m[f] = lora[:, f*32:+32] @ maa_w2[f]  (z=4, K=32)
  gemm_hl3<<<dim3(18, 12, 4), blk, 0, stream>>>(lts, lts + 294912, w2T, w2T + 98304, m,
                                                32, 128, 32, 768, 32, 24576, BTC);
  mix4<<<6912, blk, 0, stream>>>(x, xx, m, maa_rg, maa_wa, maa_k, maa_v, x4s);
  // r,k,v (z=3, 768x768)
  gemm_hl3<<<dim3(18, 12, 3), blk, 0, stream>>>(x4s, x4s + 4 * BTC, Wb, Wb + 2359296L, rbuf,
                                                768, 768, 768, 768, BTC, 589824, BTC);
  // wlora = xwa @ [wd1|a1|ma1|mk1]  (N=112)
  gemm_hl<<<dim3(36, 2, 1), blk, 0, stream>>>(x4s + 3 * BTC, x4s + 7 * BTC, wcat1, wcat1 + 86016,
                                              wlora, 112, 768, 768, 768, 112, 0, 0, 0);
  // glora = xrg @ g1  (N=128)
  gemm_hl3<<<dim3(18, 2, 1), blk, 0, stream>>>(x4s, x4s + 4 * BTC, g1T, g1T + 98304, glora,
                                               768, 768, 768, 128, 0, 0, 0);
  // kklora = xk @ kk1  (N=16)
  gemm_hl<<<dim3(36, 1, 1), blk, 0, stream>>>(x4s + BTC, x4s + 5 * BTC, kk1T, kk1T + 12288,
                                              kklora, 16, 768, 768, 768, 16, 0, 0, 0);
  build_a2<<<2592, blk, 0, stream>>>(wlora, kklora, glora, A2s, glss);
  // wraw = tanh(wlora[:,0:64]) @ wd2  (K=64)
  gemm_hl3<<<dim3(18, 12, 1), blk, 0, stream>>>(A2s, A2s + 368640, wd2T, wd2T + 49152, wrawb,
                                                64, 160, 64, 768, 0, 0, 0);
  // araw/maraw/mkraw/kkraw  (z=4, K=32 zero-padded)
  gemm_hl3<<<dim3(18, 12, 4), blk, 0, stream>>>(A2s + 64, A2s + 368640 + 64, armk2T,
                                                armk2T + 98304, m, 32, 160, 32, 768,
                                                16, 24576, BTC);
  // g = sigmoid(glora) @ g2  (K=128)
  gemm_hl3<<<dim3(18, 12, 1), blk, 0, stream>>>(glss, glss + 294912, g2T, g2T + 98304, gbuf,
                                                128, 128, 128, 768, 0, 0, 0);
  post_rwkv<<<6912, blk, 0, stream>>>(kbuf, wrawb, w0, a0, ma0, mk0,
                                      m, m + BTC, m + 2 * BTC, m + 3 * BTC);
  wkv7<<<192, dim3(128), 0, stream>>>(rbuf, m + 2 * BTC, m + 3 * BTC, vbuf, m, m + BTC, ybuf);
  gn_bonus_gate<<<6912, blk, 0, stream>>>(ybuf, rbuf, m + 3 * BTC, vbuf, gbuf, faaaa,
                                          lns, lnb, ygs);
  // out = (y*g) @ Wo
  gemm_hl3<<<dim3(18, 12, 1), blk, 0, stream>>>(ygs, ygs + BTC, Wb + 3L * 589824,
                                                Wb + 2359296L + 3L * 589824, (float*)d_out,
                                                768, 768, 768, 768, 0, 0, 0);
}

// Round 9
// 395.048 us; speedup vs baseline: 1.3256x; 1.1366x over previous
//
#include <hip/hip_runtime.h>
#include <stdint.h>

#define Hh 12
#define Cc 768
#define Tt 576
#define BTC 1769472L
#define HI_ 24
#define WI_ 24
#define CH 16
#define NCH 36
#define RB 16

typedef unsigned int uint;
typedef unsigned short ushort;
typedef __attribute__((ext_vector_type(8))) short short8;
typedef __attribute__((ext_vector_type(4))) float f32x4;

__device__ __forceinline__ ushort f2b(float f) {
  uint u = __float_as_uint(f);
  u += 0x7FFFu + ((u >> 16) & 1u);
  return (ushort)(u >> 16);
}
__device__ __forceinline__ float b2f(ushort h) { return __uint_as_float(((uint)h) << 16); }
__device__ __forceinline__ float sigm(float x) { return 1.0f / (1.0f + __expf(-x)); }

__device__ __forceinline__ float dppx1(float x) {
  return __int_as_float(__builtin_amdgcn_mov_dpp(__float_as_int(x), 0xB1, 0xF, 0xF, true));
}
__device__ __forceinline__ float dppx2(float x) {
  return __int_as_float(__builtin_amdgcn_mov_dpp(__float_as_int(x), 0x4E, 0xF, 0xF, true));
}
__device__ __forceinline__ float mir8(float x) {
  return __int_as_float(__builtin_amdgcn_mov_dpp(__float_as_int(x), 0x141, 0xF, 0xF, true));
}

// hi/lo convention: bf16-split buffer = hi plane [0,SZ) + lo plane [SZ,2*SZ).
#define PUT2(buf, i, SZ, vexpr)                      \
  {                                                  \
    float _v = (vexpr);                              \
    ushort _h = f2b(_v);                             \
    (buf)[i] = _h;                                   \
    (buf)[(long)(SZ) + (i)] = f2b(_v - b2f(_h));     \
  }

// ---------- multi-segment GEMM dispatcher: 128x64 tile, BK=32, bf16x3 hi/lo ----------
// Each segment: C[2304, nby*64] = A[2304,K] @ B[nby*64, K]^T with per-segment epilogue:
// epi 0: fp32 store to C. epi 1: tanh -> PUT2(O). epi 2: sigmoid -> PUT2(O).
// epi 3: mix (x + xx*(maap[c]+acc)) -> PUT2(O).
struct Seg {
  const ushort* Ah; const ushort* Al; const ushort* Bh; const ushort* Bl;
  float* C; ushort* O; const float* maap;
  long osz;
  int K, lda, ldb, ldc, nby, epi;
};
struct SegPack {
  Seg s[6];
  int cum[6];       // starting block of each segment; unused = 0x7fffffff
  const float* x; const float* xx;
};

__global__ __launch_bounds__(256) void gemm_multi(SegPack P) {
  __shared__ ushort sAh[128][40], sAl[128][40], sBh[64][40], sBl[64][40];  // 30KB
  const int bid = blockIdx.x;
  int si = 0;
#pragma unroll
  for (int i = 1; i < 6; i++) si = (bid >= P.cum[i]) ? i : si;
  const Seg sg = P.s[si];
  const int local = bid - P.cum[si];
  const int bx = local / sg.nby;
  const int by = local - bx * sg.nby;
  const int bm = bx * 128, bn = by * 64;
  const int tid = threadIdx.x;
  const int wave = tid >> 6, lane = tid & 63;
  const int wm = (wave >> 1) * 64, wn = (wave & 1) * 32;
  const int srow = tid >> 2, scol = (tid & 3) * 8;
  const int fr = lane & 15, kg = (lane >> 4) * 8;
  f32x4 acc[4][2] = {};
  const int lda = sg.lda, ldb = sg.ldb;
  const ushort* aph = sg.Ah + (long)(bm + srow) * lda + scol;
  const ushort* apl = sg.Al + (long)(bm + srow) * lda + scol;
  const ushort* bph = sg.Bh + (long)(bn + srow) * ldb + scol;
  const ushort* bpl = sg.Bl + (long)(bn + srow) * ldb + scol;
  const long a64 = 64L * lda;
  for (int k0 = 0; k0 < sg.K; k0 += 32) {
    short8 avh0 = *(const short8*)(aph + k0);
    short8 avh1 = *(const short8*)(aph + a64 + k0);
    short8 avl0 = *(const short8*)(apl + k0);
    short8 avl1 = *(const short8*)(apl + a64 + k0);
    short8 bvh0 = *(const short8*)(bph + k0);
    short8 bvl0 = *(const short8*)(bpl + k0);
    __syncthreads();
    *(short8*)&sAh[srow][scol] = avh0;
    *(short8*)&sAh[srow + 64][scol] = avh1;
    *(short8*)&sAl[srow][scol] = avl0;
    *(short8*)&sAl[srow + 64][scol] = avl1;
    *(short8*)&sBh[srow][scol] = bvh0;
    *(short8*)&sBl[srow][scol] = bvl0;
    __syncthreads();
    short8 bfh[2], bfl[2];
#pragma unroll
    for (int ni = 0; ni < 2; ni++) {
      bfh[ni] = *(const short8*)&sBh[wn + ni * 16 + fr][kg];
      bfl[ni] = *(const short8*)&sBl[wn + ni * 16 + fr][kg];
    }
#pragma unroll
    for (int mi = 0; mi < 4; mi++) {
      short8 afh = *(const short8*)&sAh[wm + mi * 16 + fr][kg];
      short8 afl = *(const short8*)&sAl[wm + mi * 16 + fr][kg];
#pragma unroll
      for (int ni = 0; ni < 2; ni++) {
        acc[mi][ni] = __builtin_amdgcn_mfma_f32_16x16x32_bf16(afh, bfh[ni], acc[mi][ni], 0, 0, 0);
        acc[mi][ni] = __builtin_amdgcn_mfma_f32_16x16x32_bf16(afh, bfl[ni], acc[mi][ni], 0, 0, 0);
        acc[mi][ni] = __builtin_amdgcn_mfma_f32_16x16x32_bf16(afl, bfh[ni], acc[mi][ni], 0, 0, 0);
      }
    }
  }
  const int row4 = (lane >> 4) * 4;
  const int ldc = sg.ldc;
  if (sg.epi == 0) {
#pragma unroll
    for (int mi = 0; mi < 4; mi++)
#pragma unroll
      for (int ni = 0; ni < 2; ni++) {
        int gc = bn + wn + ni * 16 + fr;
        long base = (long)(bm + wm + mi * 16 + row4) * ldc + gc;
#pragma unroll
        for (int rr = 0; rr < 4; rr++) sg.C[base + (long)rr * ldc] = acc[mi][ni][rr];
      }
  } else if (sg.epi == 3) {
#pragma unroll
    for (int mi = 0; mi < 4; mi++)
#pragma unroll
      for (int ni = 0; ni < 2; ni++) {
        int gc = bn + wn + ni * 16 + fr;
        long base = (long)(bm + wm + mi * 16 + row4) * 768 + gc;
        float mc = sg.maap[gc];
#pragma unroll
        for (int rr = 0; rr < 4; rr++) {
          long ix = base + (long)rr * 768;
          float xv = P.x[ix], d = P.xx[ix];
          PUT2(sg.O, ix, sg.osz, xv + d * (mc + acc[mi][ni][rr]));
        }
      }
  } else {
    const bool istanh = (sg.epi == 1);
#pragma unroll
    for (int mi = 0; mi < 4; mi++)
#pragma unroll
      for (int ni = 0; ni < 2; ni++) {
        int gc = bn + wn + ni * 16 + fr;
        long base = (long)(bm + wm + mi * 16 + row4) * ldc + gc;
#pragma unroll
        for (int rr = 0; rr < 4; rr++) {
          float v = acc[mi][ni][rr];
          v = istanh ? tanhf(v) : sigm(v);
          PUT2(sg.O, base + (long)rr * ldc, sg.osz, v);
        }
      }
  }
}

// ---------- weight prep ----------
__global__ __launch_bounds__(256) void conv_bigw(const float* __restrict__ Wr,
                                                 const float* __restrict__ Wk,
                                                 const float* __restrict__ Wv,
                                                 const float* __restrict__ Wo,
                                                 ushort* __restrict__ Wb) {
  long idx = (long)blockIdx.x * 256 + threadIdx.x;  // < 4*589824
  const long WSZ = 589824;
  int seg = (int)(idx / WSZ);
  long off = idx % WSZ;
  const float* s = (seg == 0) ? Wr : (seg == 1) ? Wk : (seg == 2) ? Wv : Wo;
  PUT2(Wb, idx, 2359296L, s[off]);
}

__global__ __launch_bounds__(256) void prep_smallw(
    const float* maa_w1, const float* maa_w2, const float* wd1, const float* wd2,
    const float* a1, const float* a2, const float* kk1, const float* kk2,
    const float* g1, const float* g2, const float* ma1, const float* ma2,
    const float* mk1, const float* mk2, ushort* w1T, ushort* w2T, ushort* wcat1,
    ushort* kk1T, ushort* g1T, ushort* wd2T, ushort* armk2T, ushort* g2T) {
  int idx = blockIdx.x * 256 + threadIdx.x;
  if (idx < 98304) { int n = idx / 768, c = idx % 768; PUT2(w1T, idx, 98304, maa_w1[c * 128 + n]); return; }
  idx -= 98304;
  if (idx < 98304) {
    int f = idx / 24576, r = idx % 24576; int n = r / 32, d = r % 32;
    PUT2(w2T, idx, 98304, maa_w2[(f * 32 + d) * 768 + n]); return;
  }
  idx -= 98304;
  // wcat1: 128x768, rows 0-63 wd1, 64-79 a1, 80-95 ma1, 96-111 mk1, 112-127 zero
  if (idx < 49152) { int n = idx / 768, c = idx % 768; PUT2(wcat1, idx, 98304, wd1[c * 64 + n]); return; }
  idx -= 49152;
  if (idx < 12288) { int n = idx / 768, c = idx % 768; PUT2(wcat1, 49152 + idx, 98304, a1[c * 16 + n]); return; }
  idx -= 12288;
  if (idx < 12288) { int n = idx / 768, c = idx % 768; PUT2(wcat1, 61440 + idx, 98304, ma1[c * 16 + n]); return; }
  idx -= 12288;
  if (idx < 12288) { int n = idx / 768, c = idx % 768; PUT2(wcat1, 73728 + idx, 98304, mk1[c * 16 + n]); return; }
  idx -= 12288;
  if (idx < 12288) { wcat1[86016 + idx] = 0; wcat1[98304 + 86016 + idx] = 0; return; }
  idx -= 12288;
  // kk1T: 64x768, rows 0-15 kk1, 16-63 zero
  if (idx < 12288) { int n = idx / 768, c = idx % 768; PUT2(kk1T, idx, 49152, kk1[c * 16 + n]); return; }
  idx -= 12288;
  if (idx < 36864) { kk1T[12288 + idx] = 0; kk1T[49152 + 12288 + idx] = 0; return; }
  idx -= 36864;
  if (idx < 98304) { int n = idx / 768, c = idx % 768; PUT2(g1T, idx, 98304, g1[c * 128 + n]); return; }
  idx -= 98304;
  if (idx < 49152) { int n = idx / 64, d = idx % 64; PUT2(wd2T, idx, 49152, wd2[d * 768 + n]); return; }
  idx -= 49152;
  if (idx < 98304) {
    int f = idx / 24576, r = idx % 24576; int n = r / 32, d = r % 32;
    const float* s = (f == 0) ? a2 : (f == 1) ? ma2 : (f == 2) ? mk2 : kk2;
    float v = (d < 16) ? s[d * 768 + n] : 0.0f;
    PUT2(armk2T, idx, 98304, v); return;
  }
  idx -= 98304;
  if (idx < 98304) { int n = idx / 128, d = idx % 128; PUT2(g2T, idx, 98304, g2[d * 768 + n]); }
}

// ---------- elementwise ----------
__global__ __launch_bounds__(256) void qshift_mix(const float* __restrict__ x,
                                                  const float* __restrict__ maa_x,
                                                  float* __restrict__ xx,
                                                  ushort* __restrict__ xxxs) {
  long idx = (long)blockIdx.x * 256 + threadIdx.x;  // < BTC
  int c = (int)(idx % Cc);
  int bt = (int)(idx / Cc);
  int t = bt % Tt;
  int hh = t / WI_, ww = t % WI_;
  int q = c / 192;
  float s = 0.f;
  if (q == 0) { if (ww > 0) s = x[idx - Cc]; }
  else if (q == 1) { if (ww < WI_ - 1) s = x[idx + Cc]; }
  else if (q == 2) { if (hh > 0) s = x[idx - (long)WI_ * Cc]; }
  else { if (hh < HI_ - 1) s = x[idx + (long)WI_ * Cc]; }
  float xv = x[idx];
  float d = s - xv;
  xx[idx] = d;
  PUT2(xxxs, idx, BTC, xv + d * maa_x[c]);
}

__global__ __launch_bounds__(256) void build_a2(const float* __restrict__ wlora,
                                                const float* __restrict__ kklora,
                                                ushort* __restrict__ A2s) {
  int idx = blockIdx.x * 256 + threadIdx.x;  // < 368640
  int bt = idx / 160, col = idx % 160;
  float v;
  if (col < 64) v = tanhf(wlora[bt * 128 + col]);
  else if (col < 112) v = wlora[bt * 128 + col];
  else if (col < 128) v = tanhf(kklora[bt * 64 + (col - 112)]);
  else v = 0.0f;
  PUT2(A2s, idx, 368640, v);
}

// one wave per (bt,h); writes aa/bb/decay/k3 IN PLACE over araw/maraw/mkraw/kkraw.
__global__ __launch_bounds__(256) void post_rwkv(
    const float* __restrict__ k, const float* __restrict__ wraw, const float* __restrict__ w0,
    const float* __restrict__ a0, const float* __restrict__ ma0, const float* __restrict__ mk0,
    float* araw, float* maraw, float* mkraw, float* kkraw) {
  int gw = blockIdx.x * 4 + (threadIdx.x >> 6);
  int j = threadIdx.x & 63;
  int bt = gw / Hh, h = gw % Hh;
  int c = h * 64 + j;
  long idx = (long)bt * Cc + c;
  float kv = k[idx];
  float kkv = kv + kkraw[idx];
  float ss = kkv * kkv;
  for (int mm = 1; mm < 64; mm <<= 1) ss += __shfl_xor(ss, mm, 64);
  float rn = 1.0f / fmaxf(sqrtf(ss), 1e-12f);
  float kkn = kkv * rn;
  float z = w0[c] + wraw[idx];
  float w = fminf(z, 0.f) - log1pf(__expf(-fabsf(z))) - 0.5f;
  float a = sigm(a0[c] + araw[idx]);
  float ma = sigm(ma0[c] + maraw[idx]);
  float mk = sigm(mk0[c] + mkraw[idx]);
  float k2 = kv * ma + kv * a * (1.f - ma);
  float k3 = k2 * __expf(fminf(w * mk, 0.f));
  araw[idx] = -kkn;          // aa
  maraw[idx] = kkn * a;      // bb
  mkraw[idx] = __expf(w);    // decay d
  kkraw[idx] = k3;           // final k
}

// ---------- WKV7: ROW-SPLIT, 192 blocks, 128 threads; DPP-only reduce + X/Y prefetch ----------
__global__ __launch_bounds__(128, 1) void wkv7(const float* __restrict__ r,
                                               const float* __restrict__ dd,
                                               const float* __restrict__ kk,
                                               const float* __restrict__ vv,
                                               const float* __restrict__ aa,
                                               const float* __restrict__ bb,
                                               float* __restrict__ y) {
  __shared__ float sc[2][5][CH][64];
  __shared__ float sv[2][CH][RB];
  const int blk = blockIdx.x;
  const int bh = blk >> 2;
  const int rb = blk & 3;
  const int b = bh / Hh, h = bh % Hh;
  const int tid = threadIdx.x;
  const int wave = tid >> 6, lane = tid & 63;
  const int rl = lane >> 3, cg = lane & 7;
  const int row = rb * RB + wave * 8 + rl;
  const int cb = cg * 8;
  const int vri = wave * 8 + rl;
  const long vecbase = ((long)b * Tt) * Cc + h * 64;
  float* py = y + vecbase + row;
  const float* gp[5] = {r, dd, kk, aa, bb};
  float S[8];
#pragma unroll
  for (int u = 0; u < 8; u++) S[u] = 0.f;
  f32x4 gq[10];
  float gv[2];
  f32x4 Xq[10], Yq[10];
  float Xv, Yv;

#define SLOAD(t0)                                                              \
  {                                                                            \
    _Pragma("unroll") for (int q = 0; q < 10; q++) {                           \
      const int arr = q >> 1;                                                  \
      const int i2 = ((q & 1) << 7) + tid;                                     \
      gq[q] = *(const f32x4*)(gp[arr] + vecbase + (long)((t0) + (i2 >> 4)) * Cc \
                              + ((i2 & 15) << 2));                             \
    }                                                                          \
    _Pragma("unroll") for (int j = 0; j < 2; j++) {                            \
      const int i2 = (j << 7) + tid;                                           \
      gv[j] = vv[vecbase + (long)((t0) + (i2 >> 4)) * Cc + rb * RB + (i2 & 15)]; \
    }                                                                          \
  }
#define SWRITE(bi)                                                             \
  {                                                                            \
    _Pragma("unroll") for (int q = 0; q < 10; q++) {                           \
      const int i2 = ((q & 1) << 7) + tid;                                     \
      *(f32x4*)&sc[bi][q >> 1][i2 >> 4][(i2 & 15) << 2] = gq[q];               \
    }                                                                          \
    _Pragma("unroll") for (int j = 0; j < 2; j++) {                            \
      const int i2 = (j << 7) + tid;                                           \
      sv[bi][i2 >> 4][i2 & 15] = gv[j];                                        \
    }                                                                          \
  }
#define LREAD(Q, Vv_, pb, t)                                                   \
  {                                                                            \
    Q[0] = *(const f32x4*)&sc[pb][3][t][cb];                                   \
    Q[1] = *(const f32x4*)&sc[pb][3][t][cb + 4];                               \
    Q[2] = *(const f32x4*)&sc[pb][1][t][cb];                                   \
    Q[3] = *(const f32x4*)&sc[pb][1][t][cb + 4];                               \
    Q[4] = *(const f32x4*)&sc[pb][2][t][cb];                                   \
    Q[5] = *(const f32x4*)&sc[pb][2][t][cb + 4];                               \
    Q[6] = *(const f32x4*)&sc[pb][4][t][cb];                                   \
    Q[7] = *(const f32x4*)&sc[pb][4][t][cb + 4];                               \
    Q[8] = *(const f32x4*)&sc[pb][0][t][cb];                                   \
    Q[9] = *(const f32x4*)&sc[pb][0][t][cb + 4];                               \
    Vv_ = sv[pb][t][vri];                                                      \
  }
#define WCOMP(Q, Vv_, yoff)                                                    \
  {                                                                            \
    float p0 = S[0] * Q[0][0] + S[4] * Q[1][0];                                \
    float p1 = S[1] * Q[0][1] + S[5] * Q[1][1];                                \
    float p2 = S[2] * Q[0][2] + S[6] * Q[1][2];                                \
    float p3 = S[3] * Q[0][3] + S[7] * Q[1][3];                                \
    float sa = (p0 + p1) + (p2 + p3);                                          \
    sa += dppx1(sa); sa += dppx2(sa); sa += mir8(sa);                          \
    float q0, q1, q2, q3;                                                      \
    S[0] = fmaf(S[0], Q[2][0], fmaf(sa, Q[6][0], Vv_ * Q[4][0])); q0 = S[0] * Q[8][0]; \
    S[1] = fmaf(S[1], Q[2][1], fmaf(sa, Q[6][1], Vv_ * Q[4][1])); q1 = S[1] * Q[8][1]; \
    S[2] = fmaf(S[2], Q[2][2], fmaf(sa, Q[6][2], Vv_ * Q[4][2])); q2 = S[2] * Q[8][2]; \
    S[3] = fmaf(S[3], Q[2][3], fmaf(sa, Q[6][3], Vv_ * Q[4][3])); q3 = S[3] * Q[8][3]; \
    S[4] = fmaf(S[4], Q[3][0], fmaf(sa, Q[7][0], Vv_ * Q[5][0])); q0 += S[4] * Q[9][0]; \
    S[5] = fmaf(S[5], Q[3][1], fmaf(sa, Q[7][1], Vv_ * Q[5][1])); q1 += S[5] * Q[9][1]; \
    S[6] = fmaf(S[6], Q[3][2], fmaf(sa, Q[7][2], Vv_ * Q[5][2])); q2 += S[6] * Q[9][2]; \
    S[7] = fmaf(S[7], Q[3][3], fmaf(sa, Q[7][3], Vv_ * Q[5][3])); q3 += S[7] * Q[9][3]; \
    float yp = (q0 + q1) + (q2 + q3);                                          \
    yp += dppx1(yp); yp += dppx2(yp); yp += mir8(yp);                          \
    if (cg == 0) py[yoff] = yp;                                                \
  }

  SLOAD(0);
  SWRITE(0);
  __syncthreads();
  SLOAD(CH);
  for (int ch = 0; ch < NCH; ch++) {
    const int pb = ch & 1;
    const long ybase = (long)ch * CH * Cc;
    LREAD(Xq, Xv, pb, 0);
#pragma unroll
    for (int t = 0; t < CH; t += 2) {
      LREAD(Yq, Yv, pb, t + 1);
      WCOMP(Xq, Xv, ybase + (long)t * Cc);
      if (t + 2 < CH) LREAD(Xq, Xv, pb, t + 2);
      WCOMP(Yq, Yv, ybase + (long)(t + 1) * Cc);
    }
    __syncthreads();
    if (ch + 1 < NCH) {
      SWRITE(pb ^ 1);
      if (ch + 2 < NCH) SLOAD((ch + 2) * CH);
    }
    __syncthreads();
  }
#undef SLOAD
#undef SWRITE
#undef LREAD
#undef WCOMP
}

// ---------- groupnorm + bonus + gate ----------
__global__ __launch_bounds__(256) void gn_bonus_gate(
    const float* __restrict__ y, const float* __restrict__ r, const float* __restrict__ k3,
    const float* __restrict__ v, const float* __restrict__ g, const float* __restrict__ faaaa,
    const float* __restrict__ lns, const float* __restrict__ lnb, ushort* __restrict__ ygs) {
  int gw = blockIdx.x * 4 + (threadIdx.x >> 6);
  int j = threadIdx.x & 63;
  int bt = gw / Hh, h = gw % Hh;
  int c = h * 64 + j;
  long idx = (long)bt * Cc + c;
  float yv = y[idx];
  float s1 = yv, s2 = yv * yv;
  float s3 = r[idx] * k3[idx] * faaaa[c];
  for (int mm = 1; mm < 64; mm <<= 1) {
    s1 += __shfl_xor(s1, mm, 64);
    s2 += __shfl_xor(s2, mm, 64);
    s3 += __shfl_xor(s3, mm, 64);
  }
  float mu = s1 * (1.f / 64.f);
  float var = s2 * (1.f / 64.f) - mu * mu;
  float xn = (yv - mu) * rsqrtf(var + 64e-5f);
  float y2 = xn * lns[c] + lnb[c] + s3 * v[idx];
  PUT2(ygs, idx, BTC, y2 * g[idx]);
}

// ---------- launch ----------
extern "C" void kernel_launch(void* const* d_in, const int* in_sizes, int n_in,
                              void* d_out, int out_size, void* d_ws, size_t ws_size,
                              hipStream_t stream) {
  const float* x = (const float*)d_in[0];
  const float* maa_x = (const float*)d_in[1];
  const float* maa_rg = (const float*)d_in[2];
  const float* maa_wa = (const float*)d_in[3];
  const float* maa_k = (const float*)d_in[4];
  const float* maa_v = (const float*)d_in[5];
  const float* maa_w1 = (const float*)d_in[6];
  const float* maa_w2 = (const float*)d_in[7];
  const float* w0 = (const float*)d_in[8];
  const float* wd1 = (const float*)d_in[9];
  const float* wd2 = (const float*)d_in[10];
  const float* a0 = (const float*)d_in[11];
  const float* a1 = (const float*)d_in[12];
  const float* a2 = (const float*)d_in[13];
  const float* kk1 = (const float*)d_in[14];
  const float* kk2 = (const float*)d_in[15];
  const float* g1 = (const float*)d_in[16];
  const float* g2 = (const float*)d_in[17];
  const float* ma0 = (const float*)d_in[18];
  const float* ma1 = (const float*)d_in[19];
  const float* ma2 = (const float*)d_in[20];
  const float* mk0 = (const float*)d_in[21];
  const float* mk1 = (const float*)d_in[22];
  const float* mk2 = (const float*)d_in[23];
  const float* faaaa = (const float*)d_in[24];
  const float* Wr = (const float*)d_in[25];
  const float* Wk = (const float*)d_in[26];
  const float* Wv = (const float*)d_in[27];
  const float* Wo = (const float*)d_in[28];
  const float* lns = (const float*)d_in[29];
  const float* lnb = (const float*)d_in[30];

  float* fw = (float*)d_ws;
  float* xx = fw;                          // BTC
  float* m = fw + BTC;                     // 4*BTC: aa/bb/dec/k3 (DISPATCH-B outputs)
  float* rbuf = fw + 5 * BTC;
  float* kbuf = fw + 6 * BTC;
  float* vbuf = fw + 7 * BTC;
  float* wrawb = fw + 8 * BTC;
  float* gbuf = fw + 9 * BTC;
  float* ybuf = fw + 10 * BTC;
  float* wlora = fw + 11 * BTC;            // 2304x128 = 294912
  float* kklora = wlora + 294912;          // 2304x64  = 147456
  ushort* ub = (ushort*)(kklora + 147456);
  ushort* xxxs = ub;   ub += 2 * BTC;
  ushort* x4s = ub;    ub += 8 * BTC;      // 4 planes hi then 4 planes lo
  ushort* lts = ub;    ub += 2 * 294912;
  ushort* A2s = ub;    ub += 2 * 368640;
  ushort* glss = ub;   ub += 2 * 294912;
  ushort* ygs = ub;    ub += 2 * BTC;
  ushort* Wb = ub;     ub += 2 * 2359296L;
  ushort* w1T = ub;    ub += 2 * 98304;
  ushort* w2T = ub;    ub += 2 * 98304;
  ushort* wcat1 = ub;  ub += 2 * 98304;    // 128x768 padded
  ushort* kk1T = ub;   ub += 2 * 49152;    // 64x768 padded
  ushort* g1T = ub;    ub += 2 * 98304;
  ushort* wd2T = ub;   ub += 2 * 49152;
  ushort* armk2T = ub; ub += 2 * 98304;
  ushort* g2T = ub;    ub += 2 * 98304;

  const int IMAX = 0x7fffffff;
  dim3 blk(256);
  conv_bigw<<<9216, blk, 0, stream>>>(Wr, Wk, Wv, Wo, Wb);
  prep_smallw<<<2688, blk, 0, stream>>>(maa_w1, maa_w2, wd1, wd2, a1, a2, kk1, kk2, g1, g2,
                                        ma1, ma2, mk1, mk2, w1T, w2T, wcat1, kk1T, g1T, wd2T,
                                        armk2T, g2T);
  qshift_mix<<<6912, blk, 0, stream>>>(x, maa_x, xx, xxxs);

  // D1: lora1 = tanh(xxx @ maa_w1) -> lts (bf16 hi/lo). 36 blocks.
  {
    SegPack P = {};
    P.s[0] = {xxxs, xxxs + BTC, w1T, w1T + 98304, nullptr, lts, nullptr,
              294912, 768, 768, 768, 128, 2, 1};
    P.cum[0] = 0;
    for (int i = 1; i < 6; i++) P.cum[i] = IMAX;
    P.x = x; P.xx = xx;
    gemm_multi<<<36, blk, 0, stream>>>(P);
  }
  // D2: x4s planes = x + xx*(maa + lora@w2). 4 segs x 216 = 864 blocks.
  {
    SegPack P = {};
    const float* maaps[4] = {maa_rg, maa_wa, maa_k, maa_v};  // f0->rg, f1->wa, f2->k, f3->v
    const int planes[4] = {0, 3, 1, 2};                      // x4s plane per f
    for (int f = 0; f < 4; f++) {
      P.s[f] = {lts + f * 32, lts + 294912 + f * 32, w2T + f * 24576,
                w2T + 98304 + f * 24576, nullptr, x4s + (long)planes[f] * BTC, maaps[f],
                4 * BTC, 32, 128, 32, 768, 12, 3};
      P.cum[f] = f * 216;
    }
    for (int i = 4; i < 6; i++) P.cum[i] = IMAX;
    P.x = x; P.xx = xx;
    gemm_multi<<<864, blk, 0, stream>>>(P);
  }
  // DA: r,k,v + wlora + glora(sigmoid->glss) + kklora. 738 blocks.
  {
    SegPack P = {};
    for (int f = 0; f < 3; f++) {
      float* cout = (f == 0) ? rbuf : (f == 1) ? kbuf : vbuf;
      P.s[f] = {x4s + (long)f * BTC, x4s + (long)(4 + f) * BTC, Wb + (long)f * 589824,
                Wb + 2359296L + (long)f * 589824, cout, nullptr, nullptr,
                0, 768, 768, 768, 768, 12, 0};
      P.cum[f] = f * 216;
    }
    P.s[3] = {x4s + 3 * BTC, x4s + 7 * BTC, wcat1, wcat1 + 98304, wlora, nullptr, nullptr,
              0, 768, 768, 768, 128, 2, 0};
    P.cum[3] = 648;
    P.s[4] = {x4s, x4s + 4 * BTC, g1T, g1T + 98304, nullptr, glss, nullptr,
              294912, 768, 768, 768, 128, 2, 2};
    P.cum[4] = 684;
    P.s[5] = {x4s + BTC, x4s + 5 * BTC, kk1T, kk1T + 49152, kklora, nullptr, nullptr,
              0, 768, 768, 768, 64, 1, 0};
    P.cum[5] = 720;
    P.x = x; P.xx = xx;
    gemm_multi<<<738, blk, 0, stream>>>(P);
  }
  build_a2<<<1440, blk, 0, stream>>>(wlora, kklora, A2s);
  // DB: wraw + armk x4 + g. 1296 blocks.
  {
    SegPack P = {};
    P.s[0] = {A2s, A2s + 368640, wd2T, wd2T + 49152, wrawb, nullptr, nullptr,
              0, 64, 160, 64, 768, 12, 0};
    P.cum[0] = 0;
    for (int f = 0; f < 4; f++) {
      P.s[1 + f] = {A2s + 64 + 16 * f, A2s + 368640 + 64 + 16 * f, armk2T + f * 24576,
                    armk2T + 98304 + f * 24576, m + (long)f * BTC, nullptr, nullptr,
                    0, 32, 160, 32, 768, 12, 0};
      P.cum[1 + f] = 216 + f * 216;
    }
    P.s[5] = {glss, glss + 294912, g2T, g2T + 98304, gbuf, nullptr, nullptr,
              0, 128, 128, 128, 768, 12, 0};
    P.cum[5] = 1080;
    P.x = x; P.xx = xx;
    gemm_multi<<<1296, blk, 0, stream>>>(P);
  }
  post_rwkv<<<6912, blk, 0, stream>>>(kbuf, wrawb, w0, a0, ma0, mk0,
                                      m, m + BTC, m + 2 * BTC, m + 3 * BTC);
  wkv7<<<192, dim3(128), 0, stream>>>(rbuf, m + 2 * BTC, m + 3 * BTC, vbuf, m, m + BTC, ybuf);
  gn_bonus_gate<<<6912, blk, 0, stream>>>(ybuf, rbuf, m + 3 * BTC, vbuf, gbuf, faaaa,
                                          lns, lnb, ygs);
  // DWo: out = (y*g) @ Wo. 216 blocks.
  {
    SegPack P = {};
    P.s[0] = {ygs, ygs + BTC, Wb + 3L * 589824, Wb + 2359296L + 3L * 589824,
              (float*)d_out, nullptr, nullptr, 0, 768, 768, 768, 768, 12, 0};
    P.cum[0] = 0;
    for (int i = 1; i < 6; i++) P.cum[i] = IMAX;
    P.x = x; P.xx = xx;
    gemm_multi<<<216, blk, 0, stream>>>(P);
  }
}